// Round 6
// baseline (274.017 us; speedup 1.0000x reference)
//
#include <hip/hip_runtime.h>
#include <hip/hip_cooperative_groups.h>
#include <math.h>

namespace cg = cooperative_groups;

// ---------------- problem constants ----------------
#define CIN   512
#define NOUT  123      // DEPTH + CT
#define DEPN  59
#define CT    64
#define B_    4
#define N_    6
#define FH    16
#define FW    44
#define HW    704      // FH*FW
#define NPIX  (B_*N_*HW)          // 16896
#define NX    128
#define BEV_ELEMS (B_*CT*NX*NX)   // 4,194,304
#define DEPTH_OFF BEV_ELEMS

// ws layout (float offsets). Double region first (8B aligned at base).
#define TDREC   40
#define WS_WB   1920                       // bf16 weight [128 o][512 c]
#define WS_PS   (WS_WB + 32768)            // p-slab  [row = bw*96 + n*16+h][64] (cols 0..58)
#define WS_FS   (WS_PS + NPIX*64)          // f-slab  [row][64]

#define GRID    512                        // == 2 blocks/CU co-residency bound
#define K1TILES 264                        // 11 pixcols x 24 bn
#define P2TILES (B_*FW*4)                  // 704

typedef short bf16x8 __attribute__((ext_vector_type(8)));
typedef float f32x4  __attribute__((ext_vector_type(4)));

__device__ inline unsigned short f2bf(float f) {   // RNE f32->bf16
    unsigned u = __float_as_uint(f);
    return (unsigned short)((u + 0x7fffu + ((u >> 16) & 1u)) >> 16);
}

__device__ inline void inv3d(const double* m, double* o) {
    #pragma clang fp contract(off)
    double c00 = m[4]*m[8] - m[5]*m[7];
    double c01 = m[5]*m[6] - m[3]*m[8];
    double c02 = m[3]*m[7] - m[4]*m[6];
    double det = m[0]*c00 + m[1]*c01 + m[2]*c02;
    o[0] = c00/det; o[1] = (m[2]*m[7]-m[1]*m[8])/det; o[2] = (m[1]*m[5]-m[2]*m[4])/det;
    o[3] = c01/det; o[4] = (m[0]*m[8]-m[2]*m[6])/det; o[5] = (m[2]*m[3]-m[0]*m[5])/det;
    o[6] = c02/det; o[7] = (m[1]*m[6]-m[0]*m[7])/det; o[8] = (m[0]*m[4]-m[1]*m[3])/det;
}
__device__ inline void mm3d(const double* a, const double* b, double* o) {
    #pragma clang fp contract(off)
    for (int i = 0; i < 3; ++i)
        for (int k = 0; k < 3; ++k)
            o[i*3+k] = (a[i*3+0]*b[0*3+k] + a[i*3+1]*b[1*3+k]) + a[i*3+2]*b[2*3+k];
}

// ---------------- fused kernel: P0 prep | P1 gemm+softmax (+BEV zero) | P2 pool ----------------
#define K1A   4608                 // A tile shorts (64*72)
#define K1T   13824                // shorts per buf (A + 128*72)
#define SMEM_BYTES 55296           // 2 bufs * K1T * 2B ; P2 needs 42,944

__global__ __launch_bounds__(256, 2) void fused(
        const float* __restrict__ x,     const float* __restrict__ rots,
        const float* __restrict__ trans, const float* __restrict__ intr,
        const float* __restrict__ prots, const float* __restrict__ ptrans,
        const float* __restrict__ bda,   const float* __restrict__ W,
        const float* __restrict__ bias,  float* __restrict__ ws,
        float* __restrict__ dout) {
    __shared__ __align__(16) unsigned char smem[SMEM_BYTES];
    cg::grid_group grid = cg::this_grid();
    const int tid = threadIdx.x;
    const int bid = blockIdx.x;

    // ================= P0: bf16 weight build + f64 transforms =================
    {
        unsigned short* wb = (unsigned short*)(ws + WS_WB);
        for (int i = bid * 256 + tid; i < 128 * CIN; i += GRID * 256) {
            int o = i >> 9, c = i & 511;
            wb[i] = (o < NOUT) ? f2bf(W[o * CIN + c]) : (unsigned short)0;
        }
        if (bid == 0 && tid < B_ * N_) {
            #pragma clang fp contract(off)
            int t = tid;
            int b = t / N_;
            double* X = (double*)(ws) + t * TDREC;
            double PR[9], Kd[9], Rd[9], Bd[9];
            for (int i = 0; i < 9; ++i) PR[i] = (double)prots[t * 9 + i];
            for (int i = 0; i < 9; ++i) Kd[i] = (double)intr[t * 9 + i];
            for (int i = 0; i < 9; ++i) Rd[i] = (double)rots[t * 9 + i];
            for (int i = 0; i < 9; ++i) Bd[i] = (double)bda[b * 9 + i];
            double iPR[9]; inv3d(PR, iPR);
            for (int i = 0; i < 9; ++i) X[i] = iPR[i];
            for (int i = 0; i < 3; ++i) X[9 + i] = (double)ptrans[t * 3 + i];
            double iK[9];  inv3d(Kd, iK);
            double comb[9]; mm3d(Rd, iK, comb);
            for (int i = 0; i < 9; ++i) X[12 + i] = comb[i];
            for (int i = 0; i < 3; ++i) X[21 + i] = (double)trans[t * 3 + i];
            for (int i = 0; i < 9; ++i) X[24 + i] = Bd[i];
        }
    }
    grid.sync();

    // ================= P1: MFMA GEMM + fused softmax (blocks 0..263) ==========
    //                     concurrent BEV zero (blocks 264..511)
    if (bid < K1TILES) {
        const int wave = tid >> 6, lane = tid & 63;
        const int l15 = lane & 15, quad = lane >> 4;
        const int bn = bid / 11;
        const int pixbase = (bid - bn * 11) * 64;
        const float* xg = x + (size_t)bn * CIN * HW + pixbase;
        const unsigned short* wbg = (const unsigned short*)(ws + WS_WB);
        const int cpack = tid >> 4;          // channel group of 4
        const int pix4 = (tid & 15) * 4;     // pixel group of 4
        const int wo  = tid >> 3;            // weight-stage row (0..31)
        const int wsub = tid & 7;            // weight-stage 16B sub-chunk
        unsigned short* s16 = (unsigned short*)smem;

        f32x4 acc[8] = {};
        float4 xr0, xr1, xr2, xr3;           // 1-deep prefetch (spill-free: ~80 VGPR)
        uint4  wr4[4];
        {   // prologue ck=0
            const float* src = xg + (size_t)(4 * cpack) * HW + pix4;
            xr0 = *(const float4*)(src);
            xr1 = *(const float4*)(src + HW);
            xr2 = *(const float4*)(src + 2 * HW);
            xr3 = *(const float4*)(src + 3 * HW);
            #pragma unroll
            for (int i = 0; i < 4; ++i)
                wr4[i] = *(const uint4*)(wbg + (size_t)(wo + 32 * i) * CIN + wsub * 8);
        }
        #pragma unroll
        for (int it = 0; it < 8; ++it) {
            const int buf = it & 1;
            unsigned short* sa = s16 + buf * K1T;     // [64][72]
            unsigned short* sb = sa + K1A;            // [128][72]
            {   // staged regs -> LDS (waits prefetch vmcnt)
                const float* f0 = (const float*)&xr0; const float* f1 = (const float*)&xr1;
                const float* f2 = (const float*)&xr2; const float* f3 = (const float*)&xr3;
                #pragma unroll
                for (int i = 0; i < 4; ++i) {
                    uint2 pk;
                    pk.x = (unsigned)f2bf(f0[i]) | ((unsigned)f2bf(f1[i]) << 16);
                    pk.y = (unsigned)f2bf(f2[i]) | ((unsigned)f2bf(f3[i]) << 16);
                    *(uint2*)&sa[(pix4 + i) * 72 + 4 * cpack] = pk;
                }
                #pragma unroll
                for (int i = 0; i < 4; ++i)
                    *(uint4*)&sb[(wo + 32 * i) * 72 + wsub * 8] = wr4[i];
            }
            if (it < 7) {   // prefetch next K-step (overlaps MFMA below)
                const int ck = (it + 1) * 64;
                const float* src = xg + (size_t)(ck + 4 * cpack) * HW + pix4;
                xr0 = *(const float4*)(src);
                xr1 = *(const float4*)(src + HW);
                xr2 = *(const float4*)(src + 2 * HW);
                xr3 = *(const float4*)(src + 3 * HW);
                #pragma unroll
                for (int i = 0; i < 4; ++i)
                    wr4[i] = *(const uint4*)(wbg + (size_t)(wo + 32 * i) * CIN + ck + wsub * 8);
            }
            __syncthreads();   // buf visible; buf^1 free (last read 2 iters ago)
            #pragma unroll
            for (int ks = 0; ks < 64; ks += 32) {
                const bf16x8 a = *(const bf16x8*)&sa[(wave * 16 + l15) * 72 + ks + quad * 8];
                #pragma unroll
                for (int nt = 0; nt < 8; ++nt) {
                    const bf16x8 b = *(const bf16x8*)&sb[(nt * 16 + l15) * 72 + ks + quad * 8];
                    acc[nt] = __builtin_amdgcn_mfma_f32_16x16x32_bf16(a, b, acc[nt], 0, 0, 0);
                }
            }
        }
        // epilogue: softmax + split store + p into LDS transpose (overlays buf 0;
        // safe: last buf-0 reads (it=6) precede the it=7 barrier).
        float* sred = (float*)smem;          // [64][65], 2-way banks
        const int b = bn / N_, n = bn - b * N_;
        {
            float bb[8];
            #pragma unroll
            for (int nt = 0; nt < 8; ++nt) {
                int o = nt * 16 + l15;
                bb[nt] = (o < NOUT) ? bias[o] : 0.0f;
            }
            float* ps = ws + WS_PS;
            float* fs = ws + WS_FS;
            #pragma unroll
            for (int reg = 0; reg < 4; ++reg) {
                int pixl = wave * 16 + quad * 4 + reg;
                int pix = pixbase + pixl;
                int h = pix / FW, w = pix - h * FW;
                size_t row = (size_t)(b * FW + w) * 96 + n * FH + h;
                float v[4]; float m = -INFINITY;
                #pragma unroll
                for (int nt = 0; nt < 4; ++nt) {
                    v[nt] = acc[nt][reg] + bb[nt];
                    if (nt * 16 + l15 < DEPN) m = fmaxf(m, v[nt]);
                }
                #pragma unroll
                for (int msk = 8; msk >= 1; msk >>= 1) m = fmaxf(m, __shfl_xor(m, msk, 64));
                float e[4], s = 0.0f;
                #pragma unroll
                for (int nt = 0; nt < 4; ++nt) {
                    e[nt] = (nt * 16 + l15 < DEPN) ? expf(v[nt] - m) : 0.0f;
                    s += e[nt];
                }
                #pragma unroll
                for (int msk = 8; msk >= 1; msk >>= 1) s += __shfl_xor(s, msk, 64);
                const float inv = 1.0f / s;
                #pragma unroll
                for (int nt = 0; nt < 4; ++nt) {
                    int o = nt * 16 + l15;
                    if (o < DEPN) {
                        float p = e[nt] * inv;
                        ps[row * 64 + o] = p;
                        sred[pixl * 65 + o] = p;
                    } else fs[row * 64 + (o - DEPN)] = v[nt];   // o in 59..63
                }
                #pragma unroll
                for (int nt = 4; nt < 8; ++nt) {
                    int o = nt * 16 + l15;
                    if (o < NOUT) fs[row * 64 + (o - DEPN)] = acc[nt][reg] + bb[nt];
                }
            }
        }
        __syncthreads();
        for (int o = wave; o < DEPN; o += 4)   // coalesced depth write, 256B/store
            dout[DEPTH_OFF + ((size_t)bn * DEPN + o) * HW + pixbase + lane] = sred[lane * 65 + o];
    } else {
        // BEV zero, overlapped with P1 GEMM
        float4 z = {0.f, 0.f, 0.f, 0.f};
        for (int i = (bid - K1TILES) * 256 + tid; i < BEV_ELEMS / 4; i += (GRID - K1TILES) * 256)
            *(float4*)(dout + 4 * (size_t)i) = z;
    }
    grid.sync();

    // ================= P2: Horner geometry + group-GEMM + BEV atomics =========
    {
        float*  sF   = (float*)smem;                          // [96][64]  24576 B
        float*  sP   = (float*)(smem + 24576);                // [16][100]  6400 B
        unsigned short* sv16 = (unsigned short*)(smem + 30976); // [1536]   3072 B
        double* sG   = (double*)(smem + 34048);               // [96*9]     6912 B
        double* sT   = (double*)(smem + 40960);               // [240]      1920 B
        int*    sflag = (int*)(smem + 42880);                 // [16]

        for (int t = bid; t < P2TILES; t += GRID) {
            const int bw = t >> 2;                 // 4 dchunks of same bw adjacent
            const int dch = t & 3;
            const int b = bw / FW, w = bw - b * FW;
            const int dbase = dch * 16;
            const int nd = min(16, DEPN - dbase);
            __syncthreads();   // LDS reuse guard across tiles

            {   // stage F + P(transposed, coalesced) + transforms
                const float* fsrc = ws + WS_FS + (size_t)bw * (96 * 64);
                const float* psrc = ws + WS_PS + (size_t)bw * (96 * 64);
                for (int i = tid; i < 96 * 16; i += 256) {
                    int j = i >> 4, c4 = (i & 15) * 4;
                    *(float4*)&sF[j * 64 + c4] = *(const float4*)(fsrc + j * 64 + c4);
                }
                for (int i = tid; i < 96 * 4; i += 256) {
                    int j = i >> 2, q = i & 3;
                    const float4 p4 = *(const float4*)(psrc + j * 64 + dbase + 4 * q);
                    sP[(4 * q + 0) * 100 + j] = p4.x; sP[(4 * q + 1) * 100 + j] = p4.y;
                    sP[(4 * q + 2) * 100 + j] = p4.z; sP[(4 * q + 3) * 100 + j] = p4.w;
                }
                if (tid < N_ * TDREC) sT[tid] = ((const double*)ws)[b * (N_ * TDREC) + tid];
            }
            __syncthreads();

            if (tid < 96) {   // in-tile quadratic coeffs (was k0b kernel)
                #pragma clang fp contract(off)
                int j = tid, n = j >> 4, h = j & 15;
                const double* T = &sT[n * TDREC];
                const double xs = (w == 43) ? 703.0 : (double)w * (703.0 / 43.0);
                const double ys = (double)(h * 17);
                const double u0 = xs - T[9];
                const double u1 = ys - T[10];
                double pA[3], pB[3];
                #pragma unroll
                for (int k = 0; k < 3; ++k) {
                    pA[k] = (T[3*k]*u0 + T[3*k+1]*u1) - T[3*k+2]*T[11];
                    pB[k] = T[3*k+2];
                }
                double q0c[3] = { pA[0]*pA[2], pA[0]*pB[2] + pB[0]*pA[2], pB[0]*pB[2] };
                double q1c[3] = { pA[1]*pA[2], pA[1]*pB[2] + pB[1]*pA[2], pB[1]*pB[2] };
                double q2c[3] = { pA[2], pB[2], 0.0 };
                double rc[3][3], gc[3][3];
                #pragma unroll
                for (int r = 0; r < 3; ++r)
                    #pragma unroll
                    for (int k = 0; k < 3; ++k)
                        rc[r][k] = ((T[12+3*r]*q0c[k] + T[13+3*r]*q1c[k]) + T[14+3*r]*q2c[k])
                                   + ((k == 0) ? T[21+r] : 0.0);
                #pragma unroll
                for (int g = 0; g < 3; ++g)
                    #pragma unroll
                    for (int k = 0; k < 3; ++k)
                        gc[g][k] = (T[24+3*g]*rc[0][k] + T[25+3*g]*rc[1][k]) + T[26+3*g]*rc[2][k];
                #pragma unroll
                for (int q = 0; q < 9; ++q) sG[j * 9 + q] = gc[q / 3][q % 3];
            }
            __syncthreads();

            {   // geometry: Horner evaluation (bit-matches validated f64 chain)
                const double BXY = (double)(-51.2000007629394531f);
                for (int idx = tid; idx < nd * 96; idx += 256) {
                    int dl = idx / 96, j = idx - dl * 96;
                    const double* G = &sG[j * 9];
                    const double dsv = (double)(dbase + dl + 1);
                    const double g0 = (G[2] * dsv + G[1]) * dsv + G[0];
                    const double g1 = (G[5] * dsv + G[4]) * dsv + G[3];
                    const double g2 = (G[8] * dsv + G[7]) * dsv + G[6];
                    const double fx = floor((g0 - BXY) * 1.25);   // 1.25==1/0.8 exact
                    const double fy = floor((g1 - BXY) * 1.25);
                    const bool keep = (fx >= 0.0) & (fx < 128.0) & (fy >= 0.0) & (fy < 128.0) &
                                      (g2 >= -10.0) & (g2 < 10.0);
                    sv16[idx] = keep ? (unsigned short)((int)fx * NX + (int)fy)
                                     : (unsigned short)0xFFFF;
                }
            }
            __syncthreads();

            {   // flags: parallel scan (16 threads/dl x 6 j) + shfl combine
                const int dl = tid >> 4, s = tid & 15;
                int u = -1, mix = 0;
                const int base = dl * 96 + s * 6;
                #pragma unroll
                for (int q = 0; q < 6; ++q) {
                    int v = sv16[base + q];
                    if (v != 0xFFFF) { if (u < 0) u = v; else if (v != u) mix = 1; }
                }
                #pragma unroll
                for (int msk = 1; msk < 16; msk <<= 1) {
                    int uo = __shfl_xor(u, msk, 64);
                    int mo = __shfl_xor(mix, msk, 64);
                    mix = mix | mo | ((u >= 0 && uo >= 0 && uo != u) ? 1 : 0);
                    u = (u < 0) ? uo : u;
                }
                if (s == 0 && dl < nd) sflag[dl] = mix ? -2 : u;
            }
            for (int idx = tid; idx < nd * 96; idx += 256) {
                if (sv16[idx] == 0xFFFF) {
                    int dl = idx / 96, j = idx - dl * 96;
                    sP[dl * 100 + j] = 0.0f;
                }
            }
            __syncthreads();

            // group-GEMM: C[d][c] = sum_j p[dl][j]*f[j][c]; thread = (dl, 4 ch)
            const int dl = tid >> 4, ci = tid & 15;
            if (dl < nd && sflag[dl] >= 0) {
                float ax = 0.f, ay = 0.f, az = 0.f, aw = 0.f;
                for (int jj = 0; jj < 96; jj += 4) {
                    const float4 pv = *(const float4*)&sP[dl * 100 + jj];
                    const float4 f0 = *(const float4*)&sF[(jj + 0) * 64 + 4 * ci];
                    const float4 f1 = *(const float4*)&sF[(jj + 1) * 64 + 4 * ci];
                    const float4 f2 = *(const float4*)&sF[(jj + 2) * 64 + 4 * ci];
                    const float4 f3 = *(const float4*)&sF[(jj + 3) * 64 + 4 * ci];
                    ax = fmaf(pv.x, f0.x, ax); ay = fmaf(pv.x, f0.y, ay);
                    az = fmaf(pv.x, f0.z, az); aw = fmaf(pv.x, f0.w, aw);
                    ax = fmaf(pv.y, f1.x, ax); ay = fmaf(pv.y, f1.y, ay);
                    az = fmaf(pv.y, f1.z, az); aw = fmaf(pv.y, f1.w, aw);
                    ax = fmaf(pv.z, f2.x, ax); ay = fmaf(pv.z, f2.y, ay);
                    az = fmaf(pv.z, f2.z, az); aw = fmaf(pv.z, f2.w, aw);
                    ax = fmaf(pv.w, f3.x, ax); ay = fmaf(pv.w, f3.y, ay);
                    az = fmaf(pv.w, f3.z, az); aw = fmaf(pv.w, f3.w, aw);
                }
                float* dst = dout + (((size_t)(b * CT + 4 * ci)) << 14) + sflag[dl];
                atomicAdd(dst,             ax);
                atomicAdd(dst + (1 << 14), ay);
                atomicAdd(dst + (2 << 14), az);
                atomicAdd(dst + (3 << 14), aw);
            }
            // rare per-point slow path for mixed groups
            for (int d2 = 0; d2 < nd; ++d2) {
                if (sflag[d2] == -2) {
                    int c = tid & 63, g = tid >> 6;
                    for (int jj = 0; jj < 24; ++jj) {
                        int j = g * 24 + jj;
                        int v = sv16[d2 * 96 + j];
                        if (v != 0xFFFF)
                            atomicAdd(dout + (((size_t)(b * CT + c)) << 14) + v,
                                      sP[d2 * 100 + j] * sF[j * 64 + c]);
                    }
                }
            }
        }
    }
}

// ---------------- launcher ----------------
extern "C" void kernel_launch(void* const* d_in, const int* in_sizes, int n_in,
                              void* d_out, int out_size, void* d_ws, size_t ws_size,
                              hipStream_t stream) {
    const float* x      = (const float*)d_in[0];
    const float* rots   = (const float*)d_in[1];
    const float* trans  = (const float*)d_in[2];
    const float* intr   = (const float*)d_in[3];
    const float* prots  = (const float*)d_in[4];
    const float* ptrans = (const float*)d_in[5];
    const float* bda    = (const float*)d_in[6];
    const float* W      = (const float*)d_in[7];
    const float* bias   = (const float*)d_in[8];
    float* out = (float*)d_out;
    float* ws  = (float*)d_ws;

    void* args[] = { &x, &rots, &trans, &intr, &prots, &ptrans, &bda, &W, &bias, &ws, &out };
    hipLaunchCooperativeKernel((void*)fused, dim3(GRID), dim3(256), args, 0, stream);
}

// Round 7
// 157.471 us; speedup vs baseline: 1.7401x; 1.7401x over previous
//
#include <hip/hip_runtime.h>
#include <math.h>

// ---------------- problem constants ----------------
#define CIN   512
#define NOUT  123      // DEPTH + CT
#define DEPN  59
#define CT    64
#define B_    4
#define N_    6
#define FH    16
#define FW    44
#define HW    704      // FH*FW
#define NPIX  (B_*N_*HW)          // 16896
#define NX    128
#define BEV_ELEMS (B_*CT*NX*NX)   // 4,194,304
#define DEPTH_OFF BEV_ELEMS

// ws layout (float offsets).
#define WS_WB   1920                       // bf16 weight [128 o][512 c]
#define WS_PS   (WS_WB + 32768)            // p-slab  [row = bw*96 + n*16+h][64] (cols 0..58)
#define WS_FS   (WS_PS + NPIX*64)          // f-slab  [row][64]
#define WS_GC   (WS_FS + NPIX*64)          // f64 quad coeffs [bw*96+j][9]  (even offset)

typedef short bf16x8 __attribute__((ext_vector_type(8)));
typedef float f32x4  __attribute__((ext_vector_type(4)));

__device__ inline unsigned short f2bf(float f) {   // RNE f32->bf16
    unsigned u = __float_as_uint(f);
    return (unsigned short)((u + 0x7fffu + ((u >> 16) & 1u)) >> 16);
}

__device__ inline void inv3d(const double* m, double* o) {
    #pragma clang fp contract(off)
    double c00 = m[4]*m[8] - m[5]*m[7];
    double c01 = m[5]*m[6] - m[3]*m[8];
    double c02 = m[3]*m[7] - m[4]*m[6];
    double det = m[0]*c00 + m[1]*c01 + m[2]*c02;
    o[0] = c00/det; o[1] = (m[2]*m[7]-m[1]*m[8])/det; o[2] = (m[1]*m[5]-m[2]*m[4])/det;
    o[3] = c01/det; o[4] = (m[0]*m[8]-m[2]*m[6])/det; o[5] = (m[2]*m[3]-m[0]*m[5])/det;
    o[6] = c02/det; o[7] = (m[1]*m[6]-m[0]*m[7])/det; o[8] = (m[0]*m[4]-m[1]*m[3])/det;
}
__device__ inline void mm3d(const double* a, const double* b, double* o) {
    #pragma clang fp contract(off)
    for (int i = 0; i < 3; ++i)
        for (int k = 0; k < 3; ++k)
            o[i*3+k] = (a[i*3+0]*b[0*3+k] + a[i*3+1]*b[1*3+k]) + a[i*3+2]*b[2*3+k];
}

// ---------------- K0: BEV zero + bf16 weights + in-block transforms + coeffs ----------------
// Blocks 0..65 additionally: recompute the 24 (b,n) f64 transform records into
// LDS (redundant per block, trivial cost) then emit quadratic geometry coeffs
// for their 256 ray-columns (66*256 == 16896). Removes the old k0b dispatch.
__global__ __launch_bounds__(256) void k0_prep(
        const float* __restrict__ rots,  const float* __restrict__ trans,
        const float* __restrict__ intr,  const float* __restrict__ prots,
        const float* __restrict__ ptrans,const float* __restrict__ bda,
        const float* __restrict__ W,     float* __restrict__ ws,
        float* __restrict__ dout) {
    __shared__ double sTd[24][33];
    const int tid = threadIdx.x;
    const int bid = blockIdx.x;
    int gtid = bid * 256 + tid;
    int stride = gridDim.x * 256;
    // zero the BEV region of dout (depth region fully overwritten by k1)
    float4 z = {0.f, 0.f, 0.f, 0.f};
    for (int i = gtid; i < BEV_ELEMS / 4; i += stride)
        *(float4*)(dout + 4 * (size_t)i) = z;
    unsigned short* wb = (unsigned short*)(ws + WS_WB);
    for (int i = gtid; i < 128 * CIN; i += stride) {
        int o = i >> 9, c = i & 511;
        wb[i] = (o < NOUT) ? f2bf(W[o * CIN + c]) : (unsigned short)0;
    }
    if (bid >= 66) return;
    // per-block transforms (threads 0..23), then per-thread column coeffs
    if (tid < B_ * N_) {
        #pragma clang fp contract(off)
        int t = tid, b = t / N_;
        double* X = sTd[t];
        double PR[9], Kd[9], Rd[9], Bd[9];
        for (int i = 0; i < 9; ++i) PR[i] = (double)prots[t * 9 + i];
        for (int i = 0; i < 9; ++i) Kd[i] = (double)intr[t * 9 + i];
        for (int i = 0; i < 9; ++i) Rd[i] = (double)rots[t * 9 + i];
        for (int i = 0; i < 9; ++i) Bd[i] = (double)bda[b * 9 + i];
        double iPR[9]; inv3d(PR, iPR);
        for (int i = 0; i < 9; ++i) X[i] = iPR[i];
        for (int i = 0; i < 3; ++i) X[9 + i] = (double)ptrans[t * 3 + i];
        double iK[9];  inv3d(Kd, iK);
        double comb[9]; mm3d(Rd, iK, comb);
        for (int i = 0; i < 9; ++i) X[12 + i] = comb[i];
        for (int i = 0; i < 3; ++i) X[21 + i] = (double)trans[t * 3 + i];
        for (int i = 0; i < 9; ++i) X[24 + i] = Bd[i];
    }
    __syncthreads();
    {   // quadratic coeffs for column i = (b*FW+w)*96 + j  (validated f64 chain)
        #pragma clang fp contract(off)
        int i = bid * 256 + tid;                 // < 16896
        int b = i / (FW * 96);
        int rem = i - b * (FW * 96);
        int w = rem / 96;
        int j = rem - w * 96;
        int n = j >> 4, h = j & 15;
        const double* T = sTd[b * N_ + n];
        const double xs = (w == 43) ? 703.0 : (double)w * (703.0 / 43.0);
        const double ys = (double)(h * 17);
        const double u0 = xs - T[9];
        const double u1 = ys - T[10];
        double pA[3], pB[3];
        #pragma unroll
        for (int k = 0; k < 3; ++k) {
            pA[k] = (T[3*k]*u0 + T[3*k+1]*u1) - T[3*k+2]*T[11];
            pB[k] = T[3*k+2];
        }
        double q0c[3] = { pA[0]*pA[2], pA[0]*pB[2] + pB[0]*pA[2], pB[0]*pB[2] };
        double q1c[3] = { pA[1]*pA[2], pA[1]*pB[2] + pB[1]*pA[2], pB[1]*pB[2] };
        double q2c[3] = { pA[2], pB[2], 0.0 };
        double rc[3][3], gc[3][3];
        #pragma unroll
        for (int r = 0; r < 3; ++r)
            #pragma unroll
            for (int k = 0; k < 3; ++k)
                rc[r][k] = ((T[12+3*r]*q0c[k] + T[13+3*r]*q1c[k]) + T[14+3*r]*q2c[k])
                           + ((k == 0) ? T[21+r] : 0.0);
        #pragma unroll
        for (int g = 0; g < 3; ++g)
            #pragma unroll
            for (int k = 0; k < 3; ++k)
                gc[g][k] = (T[24+3*g]*rc[0][k] + T[25+3*g]*rc[1][k]) + T[26+3*g]*rc[2][k];
        double* dst = (double*)(ws) + WS_GC / 2 + (size_t)i * 9;
        #pragma unroll
        for (int q = 0; q < 9; ++q) dst[q] = gc[q / 3][q % 3];
    }
}

// ---------------- K1: bf16 MFMA GEMM + fused softmax epilogue ----------------
// Proven structure (rounds 1/3): 256 threads, 4 waves, 64pix x 128o tile,
// LDS-staged weights shared by all waves, double-buffered, 1-deep register
// prefetch (spill-free ~88 VGPR), one barrier per K-iter, 55 KB -> 2 blocks/CU.
// Depth output written coalesced via LDS transpose overlay.
#define K1A   4608                 // A tile shorts (64*72)
#define K1T   13824                // shorts per buf (A + 128*72)
__global__ __launch_bounds__(256, 2) void k1_gemm(const float* __restrict__ x,
                                                  const float* __restrict__ bias,
                                                  float* __restrict__ ws,
                                                  float* __restrict__ dout) {
    __shared__ __align__(16) unsigned short s16[2 * K1T];   // 55,296 B
    const int tid = threadIdx.x;
    const int wave = tid >> 6, lane = tid & 63;
    const int l15 = lane & 15, quad = lane >> 4;
    const int bn = blockIdx.y;
    const int pixbase = blockIdx.x * 64;
    const float* xg = x + (size_t)bn * CIN * HW + pixbase;
    const unsigned short* wbg = (const unsigned short*)(ws + WS_WB);
    const int cpack = tid >> 4;          // channel group of 4
    const int pix4 = (tid & 15) * 4;     // pixel group of 4
    const int wo  = tid >> 3;            // weight-stage row (0..31)
    const int wsub = tid & 7;            // weight-stage 16B sub-chunk

    f32x4 acc[8] = {};
    float4 xr0, xr1, xr2, xr3;           // 1-deep prefetch
    uint4  wr4[4];
    {   // prologue ck=0
        const float* src = xg + (size_t)(4 * cpack) * HW + pix4;
        xr0 = *(const float4*)(src);
        xr1 = *(const float4*)(src + HW);
        xr2 = *(const float4*)(src + 2 * HW);
        xr3 = *(const float4*)(src + 3 * HW);
        #pragma unroll
        for (int i = 0; i < 4; ++i)
            wr4[i] = *(const uint4*)(wbg + (size_t)(wo + 32 * i) * CIN + wsub * 8);
    }
    #pragma unroll
    for (int it = 0; it < 8; ++it) {
        const int buf = it & 1;
        unsigned short* sa = s16 + buf * K1T;     // [64][72]
        unsigned short* sb = sa + K1A;            // [128][72]
        {   // staged regs -> LDS (waits prefetch vmcnt)
            const float* f0 = (const float*)&xr0; const float* f1 = (const float*)&xr1;
            const float* f2 = (const float*)&xr2; const float* f3 = (const float*)&xr3;
            #pragma unroll
            for (int i = 0; i < 4; ++i) {
                uint2 pk;
                pk.x = (unsigned)f2bf(f0[i]) | ((unsigned)f2bf(f1[i]) << 16);
                pk.y = (unsigned)f2bf(f2[i]) | ((unsigned)f2bf(f3[i]) << 16);
                *(uint2*)&sa[(pix4 + i) * 72 + 4 * cpack] = pk;
            }
            #pragma unroll
            for (int i = 0; i < 4; ++i)
                *(uint4*)&sb[(wo + 32 * i) * 72 + wsub * 8] = wr4[i];
        }
        if (it < 7) {   // prefetch next K-step (overlaps MFMA below)
            const int ck = (it + 1) * 64;
            const float* src = xg + (size_t)(ck + 4 * cpack) * HW + pix4;
            xr0 = *(const float4*)(src);
            xr1 = *(const float4*)(src + HW);
            xr2 = *(const float4*)(src + 2 * HW);
            xr3 = *(const float4*)(src + 3 * HW);
            #pragma unroll
            for (int i = 0; i < 4; ++i)
                wr4[i] = *(const uint4*)(wbg + (size_t)(wo + 32 * i) * CIN + ck + wsub * 8);
        }
        __syncthreads();   // buf visible; buf^1 free (last read 2 iters ago)
        #pragma unroll
        for (int ks = 0; ks < 64; ks += 32) {
            const bf16x8 a = *(const bf16x8*)&sa[(wave * 16 + l15) * 72 + ks + quad * 8];
            #pragma unroll
            for (int nt = 0; nt < 8; ++nt) {
                const bf16x8 b = *(const bf16x8*)&sb[(nt * 16 + l15) * 72 + ks + quad * 8];
                acc[nt] = __builtin_amdgcn_mfma_f32_16x16x32_bf16(a, b, acc[nt], 0, 0, 0);
            }
        }
    }
    // epilogue: softmax + split store + p into LDS transpose (overlays buf 0;
    // safe: last buf-0 reads (it=6) precede the it=7 barrier).
    float* sred = (float*)s16;          // [64][65], 2-way banks (free)
    const int b = bn / N_, n = bn - b * N_;
    {
        float bb[8];
        #pragma unroll
        for (int nt = 0; nt < 8; ++nt) {
            int o = nt * 16 + l15;
            bb[nt] = (o < NOUT) ? bias[o] : 0.0f;
        }
        float* ps = ws + WS_PS;
        float* fs = ws + WS_FS;
        #pragma unroll
        for (int reg = 0; reg < 4; ++reg) {
            int pixl = wave * 16 + quad * 4 + reg;
            int pix = pixbase + pixl;
            int h = pix / FW, w = pix - h * FW;
            size_t row = (size_t)(b * FW + w) * 96 + n * FH + h;
            float v[4]; float m = -INFINITY;
            #pragma unroll
            for (int nt = 0; nt < 4; ++nt) {
                v[nt] = acc[nt][reg] + bb[nt];
                if (nt * 16 + l15 < DEPN) m = fmaxf(m, v[nt]);
            }
            #pragma unroll
            for (int msk = 8; msk >= 1; msk >>= 1) m = fmaxf(m, __shfl_xor(m, msk, 64));
            float e[4], s = 0.0f;
            #pragma unroll
            for (int nt = 0; nt < 4; ++nt) {
                e[nt] = (nt * 16 + l15 < DEPN) ? expf(v[nt] - m) : 0.0f;
                s += e[nt];
            }
            #pragma unroll
            for (int msk = 8; msk >= 1; msk >>= 1) s += __shfl_xor(s, msk, 64);
            const float inv = 1.0f / s;
            #pragma unroll
            for (int nt = 0; nt < 4; ++nt) {
                int o = nt * 16 + l15;
                if (o < DEPN) {
                    float p = e[nt] * inv;
                    ps[row * 64 + o] = p;
                    sred[pixl * 65 + o] = p;
                } else fs[row * 64 + (o - DEPN)] = v[nt];   // o in 59..63
            }
            #pragma unroll
            for (int nt = 4; nt < 8; ++nt) {
                int o = nt * 16 + l15;
                if (o < NOUT) fs[row * 64 + (o - DEPN)] = acc[nt][reg] + bb[nt];
            }
        }
    }
    __syncthreads();
    for (int o = wave; o < DEPN; o += 4)   // coalesced depth write, 256B/store
        dout[DEPTH_OFF + ((size_t)bn * DEPN + o) * HW + pixbase + lane] = sred[lane * 65 + o];
}

// ---------------- K2b: Horner geometry + group-GEMM + direct BEV atomics ----------------
#define DQ2 16
__global__ __launch_bounds__(256) void k2b_geom(float* __restrict__ ws,
                                                float* __restrict__ dout) {
    __shared__ float sF[96][64];               // feats
    __shared__ float sP[DQ2][100];             // p tile, transposed, 16B-aligned rows
    __shared__ unsigned short sv16[DQ2 * 96];  // voxel id or 0xFFFF
    __shared__ __align__(16) double sG[96 * 9];// quadratic coeffs per column
    __shared__ int sflag[DQ2];
    const int tid = threadIdx.x;
    const int bw = blockIdx.x;
    const int b = bw / FW;
    const int dbase = blockIdx.y * DQ2;
    const int nd = min(DQ2, DEPN - dbase);

    {   // stage F + P(transposed, coalesced float4) + coeffs
        const float* fsrc = ws + WS_FS + (size_t)bw * (96 * 64);
        const float* psrc = ws + WS_PS + (size_t)bw * (96 * 64);
        for (int i = tid; i < 96 * 16; i += 256) {
            int j = i >> 4, c4 = (i & 15) * 4;
            *(float4*)&sF[j][c4] = *(const float4*)(fsrc + j * 64 + c4);
        }
        for (int i = tid; i < 96 * 4; i += 256) {
            int j = i >> 2, q = i & 3;
            const float4 p4 = *(const float4*)(psrc + j * 64 + dbase + 4 * q);
            sP[4 * q + 0][j] = p4.x; sP[4 * q + 1][j] = p4.y;
            sP[4 * q + 2][j] = p4.z; sP[4 * q + 3][j] = p4.w;
        }
        const double2* gsrc = (const double2*)((const double*)(ws) + WS_GC / 2
                                               + (size_t)bw * (96 * 9));
        for (int i = tid; i < 432; i += 256)
            ((double2*)sG)[i] = gsrc[i];
    }
    __syncthreads();

    {   // geometry: Horner evaluation (bit-matches validated f64 chain)
        const double BXY = (double)(-51.2000007629394531f);  // f32 value of BX-DX/2
        for (int idx = tid; idx < nd * 96; idx += 256) {
            int dl = idx / 96, j = idx - dl * 96;
            const double* G = &sG[j * 9];
            const double dsv = (double)(dbase + dl + 1);
            const double g0 = (G[2] * dsv + G[1]) * dsv + G[0];
            const double g1 = (G[5] * dsv + G[4]) * dsv + G[3];
            const double g2 = (G[8] * dsv + G[7]) * dsv + G[6];
            const double fx = floor((g0 - BXY) * 1.25);   // 1.25==1/0.8 exact
            const double fy = floor((g1 - BXY) * 1.25);
            const bool keep = (fx >= 0.0) & (fx < 128.0) & (fy >= 0.0) & (fy < 128.0) &
                              (g2 >= -10.0) & (g2 < 10.0);
            sv16[idx] = keep ? (unsigned short)((int)fx * NX + (int)fy)
                             : (unsigned short)0xFFFF;
        }
    }
    __syncthreads();

    {   // flags: parallel scan (16 threads/dl x 6 j) + shfl combine
        const int dl = tid >> 4, s = tid & 15;
        int u = -1, mix = 0;
        const int base = dl * 96 + s * 6;
        #pragma unroll
        for (int t = 0; t < 6; ++t) {
            int v = sv16[base + t];
            if (v != 0xFFFF) { if (u < 0) u = v; else if (v != u) mix = 1; }
        }
        #pragma unroll
        for (int msk = 1; msk < 16; msk <<= 1) {
            int uo = __shfl_xor(u, msk, 64);
            int mo = __shfl_xor(mix, msk, 64);
            mix = mix | mo | ((u >= 0 && uo >= 0 && uo != u) ? 1 : 0);
            u = (u < 0) ? uo : u;
        }
        if (s == 0 && dl < nd) sflag[dl] = mix ? -2 : u;
    }
    for (int idx = tid; idx < nd * 96; idx += 256) {
        if (sv16[idx] == 0xFFFF) {
            int dl = idx / 96, j = idx - dl * 96;
            sP[dl][j] = 0.0f;
        }
    }
    __syncthreads();

    // group-GEMM: C[d][c] = sum_j p[dl][j]*f[j][c]; thread = (dl, 4 ch)
    const int dl = tid >> 4, ci = tid & 15;
    if (dl < nd && sflag[dl] >= 0) {
        float ax = 0.f, ay = 0.f, az = 0.f, aw = 0.f;
        for (int jj = 0; jj < 96; jj += 4) {
            const float4 pv = *(const float4*)&sP[dl][jj];
            const float4 f0 = *(const float4*)&sF[jj + 0][4 * ci];
            const float4 f1 = *(const float4*)&sF[jj + 1][4 * ci];
            const float4 f2 = *(const float4*)&sF[jj + 2][4 * ci];
            const float4 f3 = *(const float4*)&sF[jj + 3][4 * ci];
            ax = fmaf(pv.x, f0.x, ax); ay = fmaf(pv.x, f0.y, ay);
            az = fmaf(pv.x, f0.z, az); aw = fmaf(pv.x, f0.w, aw);
            ax = fmaf(pv.y, f1.x, ax); ay = fmaf(pv.y, f1.y, ay);
            az = fmaf(pv.y, f1.z, az); aw = fmaf(pv.y, f1.w, aw);
            ax = fmaf(pv.z, f2.x, ax); ay = fmaf(pv.z, f2.y, ay);
            az = fmaf(pv.z, f2.z, az); aw = fmaf(pv.z, f2.w, aw);
            ax = fmaf(pv.w, f3.x, ax); ay = fmaf(pv.w, f3.y, ay);
            az = fmaf(pv.w, f3.z, az); aw = fmaf(pv.w, f3.w, aw);
        }
        float* dst = dout + (((size_t)(b * CT + 4 * ci)) << 14) + sflag[dl];
        atomicAdd(dst,             ax);
        atomicAdd(dst + (1 << 14), ay);
        atomicAdd(dst + (2 << 14), az);
        atomicAdd(dst + (3 << 14), aw);
    }
    // rare per-point slow path for mixed groups
    for (int d2 = 0; d2 < nd; ++d2) {
        if (sflag[d2] == -2) {
            int c = tid & 63, g = tid >> 6;
            for (int jj = 0; jj < 24; ++jj) {
                int j = g * 24 + jj;
                int v = sv16[d2 * 96 + j];
                if (v != 0xFFFF)
                    atomicAdd(dout + (((size_t)(b * CT + c)) << 14) + v,
                              sP[d2][j] * sF[j][c]);
            }
        }
    }
}

// ---------------- launcher ----------------
extern "C" void kernel_launch(void* const* d_in, const int* in_sizes, int n_in,
                              void* d_out, int out_size, void* d_ws, size_t ws_size,
                              hipStream_t stream) {
    const float* x      = (const float*)d_in[0];
    const float* rots   = (const float*)d_in[1];
    const float* trans  = (const float*)d_in[2];
    const float* intr   = (const float*)d_in[3];
    const float* prots  = (const float*)d_in[4];
    const float* ptrans = (const float*)d_in[5];
    const float* bda    = (const float*)d_in[6];
    const float* W      = (const float*)d_in[7];
    const float* bias   = (const float*)d_in[8];
    float* out = (float*)d_out;
    float* ws  = (float*)d_ws;

    k0_prep<<<512, 256, 0, stream>>>(rots, trans, intr, prots, ptrans, bda, W, ws, out);
    k1_gemm<<<dim3(HW / 64, B_ * N_), 256, 0, stream>>>(x, bias, ws, out);
    k2b_geom<<<dim3(B_ * FW, 4), 256, 0, stream>>>(ws, out);
}

// Round 8
// 150.421 us; speedup vs baseline: 1.8217x; 1.0469x over previous
//
#include <hip/hip_runtime.h>
#include <math.h>

// ---------------- problem constants ----------------
#define CIN   512
#define NOUT  123      // DEPTH + CT
#define DEPN  59
#define CT    64
#define B_    4
#define N_    6
#define FH    16
#define FW    44
#define HW    704      // FH*FW
#define NPIX  (B_*N_*HW)          // 16896
#define NX    128
#define BEV_ELEMS (B_*CT*NX*NX)   // 4,194,304
#define DEPTH_OFF BEV_ELEMS

// ws layout (float offsets).
#define WS_WB   1920                       // bf16 weight [128 o][512 c]
#define WS_PS   (WS_WB + 32768)            // p-slab  [row = bw*96 + n*16+h][64] (cols 0..58)
#define WS_FS   (WS_PS + NPIX*64)          // f-slab  [row][64]
#define WS_GC   (WS_FS + NPIX*64)          // f64 quad coeffs [bw*96+j][9]  (even offset)
#define WS_C    (WS_GC + NPIX*18)          // group rows [bw][59][64]
#define WS_VOX  (WS_C + B_*FW*DEPN*64)     // int [bw][59]

typedef short bf16x8 __attribute__((ext_vector_type(8)));
typedef float f32x4  __attribute__((ext_vector_type(4)));

__device__ inline unsigned short f2bf(float f) {   // RNE f32->bf16
    unsigned u = __float_as_uint(f);
    return (unsigned short)((u + 0x7fffu + ((u >> 16) & 1u)) >> 16);
}

__device__ inline void inv3d(const double* m, double* o) {
    #pragma clang fp contract(off)
    double c00 = m[4]*m[8] - m[5]*m[7];
    double c01 = m[5]*m[6] - m[3]*m[8];
    double c02 = m[3]*m[7] - m[4]*m[6];
    double det = m[0]*c00 + m[1]*c01 + m[2]*c02;
    o[0] = c00/det; o[1] = (m[2]*m[7]-m[1]*m[8])/det; o[2] = (m[1]*m[5]-m[2]*m[4])/det;
    o[3] = c01/det; o[4] = (m[0]*m[8]-m[2]*m[6])/det; o[5] = (m[2]*m[3]-m[0]*m[5])/det;
    o[6] = c02/det; o[7] = (m[1]*m[6]-m[0]*m[7])/det; o[8] = (m[0]*m[4]-m[1]*m[3])/det;
}
__device__ inline void mm3d(const double* a, const double* b, double* o) {
    #pragma clang fp contract(off)
    for (int i = 0; i < 3; ++i)
        for (int k = 0; k < 3; ++k)
            o[i*3+k] = (a[i*3+0]*b[0*3+k] + a[i*3+1]*b[1*3+k]) + a[i*3+2]*b[2*3+k];
}

// ---------------- K0: BEV zero + bf16 weights + in-block transforms + coeffs ----------------
__global__ __launch_bounds__(256) void k0_prep(
        const float* __restrict__ rots,  const float* __restrict__ trans,
        const float* __restrict__ intr,  const float* __restrict__ prots,
        const float* __restrict__ ptrans,const float* __restrict__ bda,
        const float* __restrict__ W,     float* __restrict__ ws,
        float* __restrict__ dout) {
    __shared__ double sTd[24][33];
    const int tid = threadIdx.x;
    const int bid = blockIdx.x;
    int gtid = bid * 256 + tid;
    int stride = gridDim.x * 256;
    // zero the BEV region of dout (depth region fully overwritten by k1)
    float4 z = {0.f, 0.f, 0.f, 0.f};
    for (int i = gtid; i < BEV_ELEMS / 4; i += stride)
        *(float4*)(dout + 4 * (size_t)i) = z;
    unsigned short* wb = (unsigned short*)(ws + WS_WB);
    for (int i = gtid; i < 128 * CIN; i += stride) {
        int o = i >> 9, c = i & 511;
        wb[i] = (o < NOUT) ? f2bf(W[o * CIN + c]) : (unsigned short)0;
    }
    if (bid >= 66) return;
    // per-block transforms (threads 0..23), then per-thread column coeffs
    if (tid < B_ * N_) {
        #pragma clang fp contract(off)
        int t = tid, b = t / N_;
        double* X = sTd[t];
        double PR[9], Kd[9], Rd[9], Bd[9];
        for (int i = 0; i < 9; ++i) PR[i] = (double)prots[t * 9 + i];
        for (int i = 0; i < 9; ++i) Kd[i] = (double)intr[t * 9 + i];
        for (int i = 0; i < 9; ++i) Rd[i] = (double)rots[t * 9 + i];
        for (int i = 0; i < 9; ++i) Bd[i] = (double)bda[b * 9 + i];
        double iPR[9]; inv3d(PR, iPR);
        for (int i = 0; i < 9; ++i) X[i] = iPR[i];
        for (int i = 0; i < 3; ++i) X[9 + i] = (double)ptrans[t * 3 + i];
        double iK[9];  inv3d(Kd, iK);
        double comb[9]; mm3d(Rd, iK, comb);
        for (int i = 0; i < 9; ++i) X[12 + i] = comb[i];
        for (int i = 0; i < 3; ++i) X[21 + i] = (double)trans[t * 3 + i];
        for (int i = 0; i < 9; ++i) X[24 + i] = Bd[i];
    }
    __syncthreads();
    {   // quadratic coeffs for column i = (b*FW+w)*96 + j  (validated f64 chain)
        #pragma clang fp contract(off)
        int i = bid * 256 + tid;                 // < 16896
        int b = i / (FW * 96);
        int rem = i - b * (FW * 96);
        int w = rem / 96;
        int j = rem - w * 96;
        int n = j >> 4, h = j & 15;
        const double* T = sTd[b * N_ + n];
        const double xs = (w == 43) ? 703.0 : (double)w * (703.0 / 43.0);
        const double ys = (double)(h * 17);
        const double u0 = xs - T[9];
        const double u1 = ys - T[10];
        double pA[3], pB[3];
        #pragma unroll
        for (int k = 0; k < 3; ++k) {
            pA[k] = (T[3*k]*u0 + T[3*k+1]*u1) - T[3*k+2]*T[11];
            pB[k] = T[3*k+2];
        }
        double q0c[3] = { pA[0]*pA[2], pA[0]*pB[2] + pB[0]*pA[2], pB[0]*pB[2] };
        double q1c[3] = { pA[1]*pA[2], pA[1]*pB[2] + pB[1]*pA[2], pB[1]*pB[2] };
        double q2c[3] = { pA[2], pB[2], 0.0 };
        double rc[3][3], gc[3][3];
        #pragma unroll
        for (int r = 0; r < 3; ++r)
            #pragma unroll
            for (int k = 0; k < 3; ++k)
                rc[r][k] = ((T[12+3*r]*q0c[k] + T[13+3*r]*q1c[k]) + T[14+3*r]*q2c[k])
                           + ((k == 0) ? T[21+r] : 0.0);
        #pragma unroll
        for (int g = 0; g < 3; ++g)
            #pragma unroll
            for (int k = 0; k < 3; ++k)
                gc[g][k] = (T[24+3*g]*rc[0][k] + T[25+3*g]*rc[1][k]) + T[26+3*g]*rc[2][k];
        double* dst = (double*)(ws) + WS_GC / 2 + (size_t)i * 9;
        #pragma unroll
        for (int q = 0; q < 9; ++q) dst[q] = gc[q / 3][q % 3];
    }
}

// ---------------- K1: bf16 MFMA GEMM + fused softmax epilogue (proven r1/r3 structure) ---
#define K1A   4608                 // A tile shorts (64*72)
#define K1T   13824                // shorts per buf (A + 128*72)
__global__ __launch_bounds__(256, 2) void k1_gemm(const float* __restrict__ x,
                                                  const float* __restrict__ bias,
                                                  float* __restrict__ ws,
                                                  float* __restrict__ dout) {
    __shared__ __align__(16) unsigned short s16[2 * K1T];   // 55,296 B
    const int tid = threadIdx.x;
    const int wave = tid >> 6, lane = tid & 63;
    const int l15 = lane & 15, quad = lane >> 4;
    const int bn = blockIdx.y;
    const int pixbase = blockIdx.x * 64;
    const float* xg = x + (size_t)bn * CIN * HW + pixbase;
    const unsigned short* wbg = (const unsigned short*)(ws + WS_WB);
    const int cpack = tid >> 4;          // channel group of 4
    const int pix4 = (tid & 15) * 4;     // pixel group of 4
    const int wo  = tid >> 3;            // weight-stage row (0..31)
    const int wsub = tid & 7;            // weight-stage 16B sub-chunk

    f32x4 acc[8] = {};
    float4 xr0, xr1, xr2, xr3;           // 1-deep prefetch
    uint4  wr4[4];
    {   // prologue ck=0
        const float* src = xg + (size_t)(4 * cpack) * HW + pix4;
        xr0 = *(const float4*)(src);
        xr1 = *(const float4*)(src + HW);
        xr2 = *(const float4*)(src + 2 * HW);
        xr3 = *(const float4*)(src + 3 * HW);
        #pragma unroll
        for (int i = 0; i < 4; ++i)
            wr4[i] = *(const uint4*)(wbg + (size_t)(wo + 32 * i) * CIN + wsub * 8);
    }
    #pragma unroll
    for (int it = 0; it < 8; ++it) {
        const int buf = it & 1;
        unsigned short* sa = s16 + buf * K1T;     // [64][72]
        unsigned short* sb = sa + K1A;            // [128][72]
        {   // staged regs -> LDS (waits prefetch vmcnt)
            const float* f0 = (const float*)&xr0; const float* f1 = (const float*)&xr1;
            const float* f2 = (const float*)&xr2; const float* f3 = (const float*)&xr3;
            #pragma unroll
            for (int i = 0; i < 4; ++i) {
                uint2 pk;
                pk.x = (unsigned)f2bf(f0[i]) | ((unsigned)f2bf(f1[i]) << 16);
                pk.y = (unsigned)f2bf(f2[i]) | ((unsigned)f2bf(f3[i]) << 16);
                *(uint2*)&sa[(pix4 + i) * 72 + 4 * cpack] = pk;
            }
            #pragma unroll
            for (int i = 0; i < 4; ++i)
                *(uint4*)&sb[(wo + 32 * i) * 72 + wsub * 8] = wr4[i];
        }
        if (it < 7) {   // prefetch next K-step (overlaps MFMA below)
            const int ck = (it + 1) * 64;
            const float* src = xg + (size_t)(ck + 4 * cpack) * HW + pix4;
            xr0 = *(const float4*)(src);
            xr1 = *(const float4*)(src + HW);
            xr2 = *(const float4*)(src + 2 * HW);
            xr3 = *(const float4*)(src + 3 * HW);
            #pragma unroll
            for (int i = 0; i < 4; ++i)
                wr4[i] = *(const uint4*)(wbg + (size_t)(wo + 32 * i) * CIN + ck + wsub * 8);
        }
        __syncthreads();   // buf visible; buf^1 free (last read 2 iters ago)
        #pragma unroll
        for (int ks = 0; ks < 64; ks += 32) {
            const bf16x8 a = *(const bf16x8*)&sa[(wave * 16 + l15) * 72 + ks + quad * 8];
            #pragma unroll
            for (int nt = 0; nt < 8; ++nt) {
                const bf16x8 b = *(const bf16x8*)&sb[(nt * 16 + l15) * 72 + ks + quad * 8];
                acc[nt] = __builtin_amdgcn_mfma_f32_16x16x32_bf16(a, b, acc[nt], 0, 0, 0);
            }
        }
    }
    // epilogue: softmax + split store + p into LDS transpose (overlays buf 0)
    float* sred = (float*)s16;          // [64][65], 2-way banks (free)
    const int b = bn / N_, n = bn - b * N_;
    {
        float bb[8];
        #pragma unroll
        for (int nt = 0; nt < 8; ++nt) {
            int o = nt * 16 + l15;
            bb[nt] = (o < NOUT) ? bias[o] : 0.0f;
        }
        float* ps = ws + WS_PS;
        float* fs = ws + WS_FS;
        #pragma unroll
        for (int reg = 0; reg < 4; ++reg) {
            int pixl = wave * 16 + quad * 4 + reg;
            int pix = pixbase + pixl;
            int h = pix / FW, w = pix - h * FW;
            size_t row = (size_t)(b * FW + w) * 96 + n * FH + h;
            float v[4]; float m = -INFINITY;
            #pragma unroll
            for (int nt = 0; nt < 4; ++nt) {
                v[nt] = acc[nt][reg] + bb[nt];
                if (nt * 16 + l15 < DEPN) m = fmaxf(m, v[nt]);
            }
            #pragma unroll
            for (int msk = 8; msk >= 1; msk >>= 1) m = fmaxf(m, __shfl_xor(m, msk, 64));
            float e[4], s = 0.0f;
            #pragma unroll
            for (int nt = 0; nt < 4; ++nt) {
                e[nt] = (nt * 16 + l15 < DEPN) ? expf(v[nt] - m) : 0.0f;
                s += e[nt];
            }
            #pragma unroll
            for (int msk = 8; msk >= 1; msk >>= 1) s += __shfl_xor(s, msk, 64);
            const float inv = 1.0f / s;
            #pragma unroll
            for (int nt = 0; nt < 4; ++nt) {
                int o = nt * 16 + l15;
                if (o < DEPN) {
                    float p = e[nt] * inv;
                    ps[row * 64 + o] = p;
                    sred[pixl * 65 + o] = p;
                } else fs[row * 64 + (o - DEPN)] = v[nt];   // o in 59..63
            }
            #pragma unroll
            for (int nt = 4; nt < 8; ++nt) {
                int o = nt * 16 + l15;
                if (o < NOUT) fs[row * 64 + (o - DEPN)] = acc[nt][reg] + bb[nt];
            }
        }
    }
    __syncthreads();
    for (int o = wave; o < DEPN; o += 4)   // coalesced depth write, 256B/store
        dout[DEPTH_OFF + ((size_t)bn * DEPN + o) * HW + pixbase + lane] = sred[lane * 65 + o];
}

// ---------------- K2b: Horner geometry + group-GEMM -> SEQUENTIAL C-slab ----------------
// v8: group sums stream to WS_C (float4, sequential) + voxel id to WS_VOX.
// No scattered dout atomics (that was 18MB of random 64B HBM writeback = k2b's
// entire 46us). Mixed groups (rare) still atomic into the zeroed dout, which
// k2c then += on top of -- ordering correct across dispatches.
#define DQ2 16
__global__ __launch_bounds__(256) void k2b_geom(float* __restrict__ ws,
                                                float* __restrict__ dout) {
    __shared__ float sF[96][64];               // feats
    __shared__ float sP[DQ2][100];             // p tile, transposed, 16B-aligned rows
    __shared__ unsigned short sv16[DQ2 * 96];  // voxel id or 0xFFFF
    __shared__ __align__(16) double sG[96 * 9];// quadratic coeffs per column
    __shared__ int sflag[DQ2];
    const int tid = threadIdx.x;
    const int bw = blockIdx.x;
    const int b = bw / FW;
    const int dbase = blockIdx.y * DQ2;
    const int nd = min(DQ2, DEPN - dbase);

    {   // stage F + P(transposed, coalesced float4) + coeffs
        const float* fsrc = ws + WS_FS + (size_t)bw * (96 * 64);
        const float* psrc = ws + WS_PS + (size_t)bw * (96 * 64);
        for (int i = tid; i < 96 * 16; i += 256) {
            int j = i >> 4, c4 = (i & 15) * 4;
            *(float4*)&sF[j][c4] = *(const float4*)(fsrc + j * 64 + c4);
        }
        for (int i = tid; i < 96 * 4; i += 256) {
            int j = i >> 2, q = i & 3;
            const float4 p4 = *(const float4*)(psrc + j * 64 + dbase + 4 * q);
            sP[4 * q + 0][j] = p4.x; sP[4 * q + 1][j] = p4.y;
            sP[4 * q + 2][j] = p4.z; sP[4 * q + 3][j] = p4.w;
        }
        const double2* gsrc = (const double2*)((const double*)(ws) + WS_GC / 2
                                               + (size_t)bw * (96 * 9));
        for (int i = tid; i < 432; i += 256)
            ((double2*)sG)[i] = gsrc[i];
    }
    __syncthreads();

    {   // geometry: Horner evaluation (bit-matches validated f64 chain)
        const double BXY = (double)(-51.2000007629394531f);  // f32 value of BX-DX/2
        for (int idx = tid; idx < nd * 96; idx += 256) {
            int dl = idx / 96, j = idx - dl * 96;
            const double* G = &sG[j * 9];
            const double dsv = (double)(dbase + dl + 1);
            const double g0 = (G[2] * dsv + G[1]) * dsv + G[0];
            const double g1 = (G[5] * dsv + G[4]) * dsv + G[3];
            const double g2 = (G[8] * dsv + G[7]) * dsv + G[6];
            const double fx = floor((g0 - BXY) * 1.25);   // 1.25==1/0.8 exact
            const double fy = floor((g1 - BXY) * 1.25);
            const bool keep = (fx >= 0.0) & (fx < 128.0) & (fy >= 0.0) & (fy < 128.0) &
                              (g2 >= -10.0) & (g2 < 10.0);
            sv16[idx] = keep ? (unsigned short)((int)fx * NX + (int)fy)
                             : (unsigned short)0xFFFF;
        }
    }
    __syncthreads();

    {   // flags: parallel scan (16 threads/dl x 6 j) + shfl combine
        const int dl = tid >> 4, s = tid & 15;
        int u = -1, mix = 0;
        const int base = dl * 96 + s * 6;
        #pragma unroll
        for (int t = 0; t < 6; ++t) {
            int v = sv16[base + t];
            if (v != 0xFFFF) { if (u < 0) u = v; else if (v != u) mix = 1; }
        }
        #pragma unroll
        for (int msk = 1; msk < 16; msk <<= 1) {
            int uo = __shfl_xor(u, msk, 64);
            int mo = __shfl_xor(mix, msk, 64);
            mix = mix | mo | ((u >= 0 && uo >= 0 && uo != u) ? 1 : 0);
            u = (u < 0) ? uo : u;
        }
        if (s == 0 && dl < nd) sflag[dl] = mix ? -2 : u;
    }
    for (int idx = tid; idx < nd * 96; idx += 256) {
        if (sv16[idx] == 0xFFFF) {
            int dl = idx / 96, j = idx - dl * 96;
            sP[dl][j] = 0.0f;
        }
    }
    __syncthreads();

    // group-GEMM: C[d][c] = sum_j p[dl][j]*f[j][c]; thread = (dl, 4 ch)
    const int dl = tid >> 4, ci = tid & 15;
    if (dl < nd) {
        const int flag = sflag[dl];
        if (ci == 0)   // voxel entry for k2c (-1: invalid or mixed-handled)
            ((int*)(ws + WS_VOX))[bw * DEPN + dbase + dl] = (flag >= 0) ? flag : -1;
        if (flag >= 0) {
            float ax = 0.f, ay = 0.f, az = 0.f, aw = 0.f;
            for (int jj = 0; jj < 96; jj += 4) {
                const float4 pv = *(const float4*)&sP[dl][jj];
                const float4 f0 = *(const float4*)&sF[jj + 0][4 * ci];
                const float4 f1 = *(const float4*)&sF[jj + 1][4 * ci];
                const float4 f2 = *(const float4*)&sF[jj + 2][4 * ci];
                const float4 f3 = *(const float4*)&sF[jj + 3][4 * ci];
                ax = fmaf(pv.x, f0.x, ax); ay = fmaf(pv.x, f0.y, ay);
                az = fmaf(pv.x, f0.z, az); aw = fmaf(pv.x, f0.w, aw);
                ax = fmaf(pv.y, f1.x, ax); ay = fmaf(pv.y, f1.y, ay);
                az = fmaf(pv.y, f1.z, az); aw = fmaf(pv.y, f1.w, aw);
                ax = fmaf(pv.z, f2.x, ax); ay = fmaf(pv.z, f2.y, ay);
                az = fmaf(pv.z, f2.z, az); aw = fmaf(pv.z, f2.w, aw);
                ax = fmaf(pv.w, f3.x, ax); ay = fmaf(pv.w, f3.y, ay);
                az = fmaf(pv.w, f3.z, az); aw = fmaf(pv.w, f3.w, aw);
            }
            float4 st = { ax, ay, az, aw };
            *(float4*)&ws[WS_C + ((size_t)(bw * DEPN + dbase + dl)) * 64 + 4 * ci] = st;
        }
    }
    // rare per-point slow path for mixed groups (atomics into zeroed dout; k2c
    // then adds group sums on top -- later dispatch, ordering safe)
    for (int d2 = 0; d2 < nd; ++d2) {
        if (sflag[d2] == -2) {
            int c = tid & 63, g = tid >> 6;
            for (int jj = 0; jj < 24; ++jj) {
                int j = g * 24 + jj;
                int v = sv16[d2 * 96 + j];
                if (v != 0xFFFF)
                    atomicAdd(dout + (((size_t)(b * CT + c)) << 14) + v,
                              sP[d2][j] * sF[j][c]);
            }
        }
    }
}

// ---------------- K2c: voxel-chunk gather + SEQUENTIAL BEV += ----------------
// Block = (128-voxel chunk, b). Scan the 2596 per-b group entries, accumulate
// matching rows in LDS, then dout += acc with coalesced 512B row stores.
#define CHUNK 128
__global__ __launch_bounds__(256) void k2c_scatter(const float* __restrict__ ws,
                                                   float* __restrict__ dout) {
    __shared__ float acc[64][CHUNK + 4];       // 33,792 B (pad: c*132+v banking)
    __shared__ int   sVox[FW * DEPN];          // 2596 ids, 10.4 KB
    __shared__ short sMatch[FW * DEPN];        // 5.2 KB
    __shared__ int   nMatch;
    const int tid = threadIdx.x;
    const int base = blockIdx.x * CHUNK;
    const int b = blockIdx.y;
    for (int i = tid; i < 64 * (CHUNK + 4); i += 256) (&acc[0][0])[i] = 0.0f;
    if (tid == 0) nMatch = 0;
    const int* vsrc = (const int*)(ws + WS_VOX) + b * (FW * DEPN);
    for (int i = tid; i < FW * DEPN; i += 256) sVox[i] = vsrc[i];
    __syncthreads();
    for (int i = tid; i < FW * DEPN; i += 256) {
        int v = sVox[i];
        if ((unsigned)(v - base) < CHUNK) {
            int m = atomicAdd(&nMatch, 1);
            sMatch[m] = (short)i;
        }
    }
    __syncthreads();
    const int c = tid & 63, quarter = tid >> 6;
    const int nm = nMatch;
    for (int m = quarter; m < nm; m += 4) {
        int e = sMatch[m];
        int lv = sVox[e] - base;
        float val = ws[WS_C + ((size_t)b * (FW * DEPN) + e) * 64 + c];
        atomicAdd(&acc[c][lv], val);           // LDS float atomic; nm ~ 20
    }
    __syncthreads();
    // dout += acc : per c-row 128 contiguous floats (512B coalesced per wave)
    const int wave = tid >> 6, lane = tid & 63;
    float* outb = dout + (((size_t)(b * CT)) << 14) + base;
    for (int r = wave; r < 64; r += 4) {
        float2* dst = (float2*)(outb + ((size_t)r << 14) + lane * 2);
        float2 v = *dst;
        v.x += acc[r][lane * 2];
        v.y += acc[r][lane * 2 + 1];
        *dst = v;
    }
}

// ---------------- launcher ----------------
extern "C" void kernel_launch(void* const* d_in, const int* in_sizes, int n_in,
                              void* d_out, int out_size, void* d_ws, size_t ws_size,
                              hipStream_t stream) {
    const float* x      = (const float*)d_in[0];
    const float* rots   = (const float*)d_in[1];
    const float* trans  = (const float*)d_in[2];
    const float* intr   = (const float*)d_in[3];
    const float* prots  = (const float*)d_in[4];
    const float* ptrans = (const float*)d_in[5];
    const float* bda    = (const float*)d_in[6];
    const float* W      = (const float*)d_in[7];
    const float* bias   = (const float*)d_in[8];
    float* out = (float*)d_out;
    float* ws  = (float*)d_ws;

    k0_prep<<<512, 256, 0, stream>>>(rots, trans, intr, prots, ptrans, bda, W, ws, out);
    k1_gemm<<<dim3(HW / 64, B_ * N_), 256, 0, stream>>>(x, bias, ws, out);
    k2b_geom<<<dim3(B_ * FW, 4), 256, 0, stream>>>(ws, out);
    k2c_scatter<<<dim3(NX * NX / CHUNK, B_), 256, 0, stream>>>(ws, out);
}

// Round 9
// 137.473 us; speedup vs baseline: 1.9932x; 1.0942x over previous
//
#include <hip/hip_runtime.h>
#include <math.h>

// ---------------- problem constants ----------------
#define CIN   512
#define NOUT  123      // DEPTH + CT
#define DEPN  59
#define CT    64
#define B_    4
#define N_    6
#define FH    16
#define FW    44
#define HW    704      // FH*FW
#define NPIX  (B_*N_*HW)          // 16896
#define NX    128
#define BEV_ELEMS (B_*CT*NX*NX)   // 4,194,304
#define DEPTH_OFF BEV_ELEMS

// ws layout (float offsets).
#define WS_WB   1920                       // (unused region kept for layout stability)
#define WS_PS   (WS_WB + 32768)            // p-slab  [row = bw*96 + n*16+h][64] (cols 0..58)
#define WS_FS   (WS_PS + NPIX*64)          // f-slab  [row][64]
#define WS_C    (WS_FS + NPIX*64)          // group rows [bw][59][64]
#define WS_VOX  (WS_C + B_*FW*DEPN*64)     // int [bw][59]
#define WS_MIXF (WS_VOX + B_*FW*DEPN)      // int mixed-group flag

typedef short bf16x8 __attribute__((ext_vector_type(8)));
typedef float f32x4  __attribute__((ext_vector_type(4)));

__device__ inline unsigned short f2bf(float f) {   // RNE f32->bf16
    unsigned u = __float_as_uint(f);
    return (unsigned short)((u + 0x7fffu + ((u >> 16) & 1u)) >> 16);
}

__device__ inline void inv3d(const double* m, double* o) {
    #pragma clang fp contract(off)
    double c00 = m[4]*m[8] - m[5]*m[7];
    double c01 = m[5]*m[6] - m[3]*m[8];
    double c02 = m[3]*m[7] - m[4]*m[6];
    double det = m[0]*c00 + m[1]*c01 + m[2]*c02;
    o[0] = c00/det; o[1] = (m[2]*m[7]-m[1]*m[8])/det; o[2] = (m[1]*m[5]-m[2]*m[4])/det;
    o[3] = c01/det; o[4] = (m[0]*m[8]-m[2]*m[6])/det; o[5] = (m[2]*m[3]-m[0]*m[5])/det;
    o[6] = c02/det; o[7] = (m[1]*m[6]-m[0]*m[7])/det; o[8] = (m[0]*m[4]-m[1]*m[3])/det;
}
__device__ inline void mm3d(const double* a, const double* b, double* o) {
    #pragma clang fp contract(off)
    for (int i = 0; i < 3; ++i)
        for (int k = 0; k < 3; ++k)
            o[i*3+k] = (a[i*3+0]*b[0*3+k] + a[i*3+1]*b[1*3+k]) + a[i*3+2]*b[2*3+k];
}

// ---------------- K1: bf16 MFMA GEMM + fused softmax + BEV zero ----------------
// v9: self-contained. Weights converted f32->bf16 in the staging step (removes
// the k0 weight build + its dependency). BEV zero folded into the epilogue tail
// (grid-stride over 264 blocks). Otherwise the proven r1/r3 structure.
#define K1A   4608                 // A tile shorts (64*72)
#define K1T   13824                // shorts per buf (A + 128*72)
__global__ __launch_bounds__(256, 2) void k1_gemm(const float* __restrict__ x,
                                                  const float* __restrict__ W,
                                                  const float* __restrict__ bias,
                                                  float* __restrict__ ws,
                                                  float* __restrict__ dout) {
    __shared__ __align__(16) unsigned short s16[2 * K1T];   // 55,296 B
    const int tid = threadIdx.x;
    const int wave = tid >> 6, lane = tid & 63;
    const int l15 = lane & 15, quad = lane >> 4;
    const int bn = blockIdx.y;
    const int pixbase = blockIdx.x * 64;
    const float* xg = x + (size_t)bn * CIN * HW + pixbase;
    const int cpack = tid >> 4;          // channel group of 4
    const int pix4 = (tid & 15) * 4;     // pixel group of 4
    const int wo  = tid >> 3;            // weight-stage row (0..31)
    const int wsub = tid & 7;            // weight-stage 16B sub-chunk

    f32x4 acc[8] = {};
    float4 xr0, xr1, xr2, xr3;           // 1-deep prefetch: x tile
    float4 wf[8];                        // 1-deep prefetch: weight rows (f32)
    const float4 zf4 = {0.f, 0.f, 0.f, 0.f};
    {   // prologue ck=0
        const float* src = xg + (size_t)(4 * cpack) * HW + pix4;
        xr0 = *(const float4*)(src);
        xr1 = *(const float4*)(src + HW);
        xr2 = *(const float4*)(src + 2 * HW);
        xr3 = *(const float4*)(src + 3 * HW);
        #pragma unroll
        for (int i = 0; i < 4; ++i) {
            const int o = wo + 32 * i;
            if (o < NOUT) {
                const float* wp = W + (size_t)o * CIN + wsub * 8;
                wf[2 * i]     = *(const float4*)(wp);
                wf[2 * i + 1] = *(const float4*)(wp + 4);
            } else { wf[2 * i] = zf4; wf[2 * i + 1] = zf4; }
        }
    }
    #pragma unroll
    for (int it = 0; it < 8; ++it) {
        const int buf = it & 1;
        unsigned short* sa = s16 + buf * K1T;     // [64][72]
        unsigned short* sb = sa + K1A;            // [128][72]
        {   // staged regs -> LDS (waits prefetch vmcnt), converting to bf16
            const float* f0 = (const float*)&xr0; const float* f1 = (const float*)&xr1;
            const float* f2 = (const float*)&xr2; const float* f3 = (const float*)&xr3;
            #pragma unroll
            for (int i = 0; i < 4; ++i) {
                uint2 pk;
                pk.x = (unsigned)f2bf(f0[i]) | ((unsigned)f2bf(f1[i]) << 16);
                pk.y = (unsigned)f2bf(f2[i]) | ((unsigned)f2bf(f3[i]) << 16);
                *(uint2*)&sa[(pix4 + i) * 72 + 4 * cpack] = pk;
            }
            #pragma unroll
            for (int i = 0; i < 4; ++i) {
                const float* fw = (const float*)&wf[2 * i];
                uint4 pk;
                pk.x = (unsigned)f2bf(fw[0]) | ((unsigned)f2bf(fw[1]) << 16);
                pk.y = (unsigned)f2bf(fw[2]) | ((unsigned)f2bf(fw[3]) << 16);
                pk.z = (unsigned)f2bf(fw[4]) | ((unsigned)f2bf(fw[5]) << 16);
                pk.w = (unsigned)f2bf(fw[6]) | ((unsigned)f2bf(fw[7]) << 16);
                *(uint4*)&sb[(wo + 32 * i) * 72 + wsub * 8] = pk;
            }
        }
        if (it < 7) {   // prefetch next K-step (overlaps MFMA below)
            const int ck = (it + 1) * 64;
            const float* src = xg + (size_t)(ck + 4 * cpack) * HW + pix4;
            xr0 = *(const float4*)(src);
            xr1 = *(const float4*)(src + HW);
            xr2 = *(const float4*)(src + 2 * HW);
            xr3 = *(const float4*)(src + 3 * HW);
            #pragma unroll
            for (int i = 0; i < 4; ++i) {
                const int o = wo + 32 * i;
                if (o < NOUT) {
                    const float* wp = W + (size_t)o * CIN + ck + wsub * 8;
                    wf[2 * i]     = *(const float4*)(wp);
                    wf[2 * i + 1] = *(const float4*)(wp + 4);
                } else { wf[2 * i] = zf4; wf[2 * i + 1] = zf4; }
            }
        }
        __syncthreads();   // buf visible; buf^1 free (last read 2 iters ago)
        #pragma unroll
        for (int ks = 0; ks < 64; ks += 32) {
            const bf16x8 a = *(const bf16x8*)&sa[(wave * 16 + l15) * 72 + ks + quad * 8];
            #pragma unroll
            for (int nt = 0; nt < 8; ++nt) {
                const bf16x8 b = *(const bf16x8*)&sb[(nt * 16 + l15) * 72 + ks + quad * 8];
                acc[nt] = __builtin_amdgcn_mfma_f32_16x16x32_bf16(a, b, acc[nt], 0, 0, 0);
            }
        }
    }
    // epilogue: softmax + split store + p into LDS transpose (overlays buf 0)
    float* sred = (float*)s16;          // [64][65], 2-way banks (free)
    const int b = bn / N_, n = bn - b * N_;
    {
        float bb[8];
        #pragma unroll
        for (int nt = 0; nt < 8; ++nt) {
            int o = nt * 16 + l15;
            bb[nt] = (o < NOUT) ? bias[o] : 0.0f;
        }
        float* ps = ws + WS_PS;
        float* fs = ws + WS_FS;
        #pragma unroll
        for (int reg = 0; reg < 4; ++reg) {
            int pixl = wave * 16 + quad * 4 + reg;
            int pix = pixbase + pixl;
            int h = pix / FW, w = pix - h * FW;
            size_t row = (size_t)(b * FW + w) * 96 + n * FH + h;
            float v[4]; float m = -INFINITY;
            #pragma unroll
            for (int nt = 0; nt < 4; ++nt) {
                v[nt] = acc[nt][reg] + bb[nt];
                if (nt * 16 + l15 < DEPN) m = fmaxf(m, v[nt]);
            }
            #pragma unroll
            for (int msk = 8; msk >= 1; msk >>= 1) m = fmaxf(m, __shfl_xor(m, msk, 64));
            float e[4], s = 0.0f;
            #pragma unroll
            for (int nt = 0; nt < 4; ++nt) {
                e[nt] = (nt * 16 + l15 < DEPN) ? expf(v[nt] - m) : 0.0f;
                s += e[nt];
            }
            #pragma unroll
            for (int msk = 8; msk >= 1; msk >>= 1) s += __shfl_xor(s, msk, 64);
            const float inv = 1.0f / s;
            #pragma unroll
            for (int nt = 0; nt < 4; ++nt) {
                int o = nt * 16 + l15;
                if (o < DEPN) {
                    float p = e[nt] * inv;
                    ps[row * 64 + o] = p;
                    sred[pixl * 65 + o] = p;
                } else fs[row * 64 + (o - DEPN)] = v[nt];   // o in 59..63
            }
            #pragma unroll
            for (int nt = 4; nt < 8; ++nt) {
                int o = nt * 16 + l15;
                if (o < NOUT) fs[row * 64 + (o - DEPN)] = acc[nt][reg] + bb[nt];
            }
        }
    }
    __syncthreads();
    for (int o = wave; o < DEPN; o += 4)   // coalesced depth write, 256B/store
        dout[DEPTH_OFF + ((size_t)bn * DEPN + o) * HW + pixbase + lane] = sred[lane * 65 + o];
    // ---- BEV zero + mixed-flag clear (tail; ordered before k2b/k2c dispatches)
    {
        const int gbid = bn * 11 + blockIdx.x;            // 0..263
        float4 z = {0.f, 0.f, 0.f, 0.f};
        for (int i = gbid * 256 + tid; i < BEV_ELEMS / 4; i += 264 * 256)
            *(float4*)(dout + 4 * (size_t)i) = z;
        if (gbid == 0 && tid == 0) ((int*)(ws + WS_MIXF))[0] = 0;
    }
}

// ---------------- K2b: in-tile transforms+coeffs + Horner geometry + group-GEMM ----------------
// v9: transforms (6 cameras of this b) and quadratic coeffs computed in-LDS
// (removes the k0 dispatch and the WS_GC round-trip). Group sums stream to
// WS_C; voxel ids to WS_VOX; mixed groups (structurally absent for this input)
// set WS_MIXF and atomic into the k1-zeroed dout.
#define DQ2 16
__global__ __launch_bounds__(256) void k2b_geom(
        const float* __restrict__ rots,  const float* __restrict__ trans,
        const float* __restrict__ intr,  const float* __restrict__ prots,
        const float* __restrict__ ptrans,const float* __restrict__ bda,
        float* __restrict__ ws,          float* __restrict__ dout) {
    __shared__ float sF[96][64];               // feats
    __shared__ float sP[DQ2][100];             // p tile, transposed, 16B-aligned rows
    __shared__ unsigned short sv16[DQ2 * 96];  // voxel id or 0xFFFF
    __shared__ __align__(16) double sG[96 * 9];// quadratic coeffs per column
    __shared__ double sTd[N_][33];             // per-camera transform records
    __shared__ int sflag[DQ2];
    const int tid = threadIdx.x;
    const int bw = blockIdx.x;
    const int b = bw / FW, w = bw - b * FW;
    const int dbase = blockIdx.y * DQ2;
    const int nd = min(DQ2, DEPN - dbase);

    {   // stage F + P(transposed, coalesced float4)
        const float* fsrc = ws + WS_FS + (size_t)bw * (96 * 64);
        const float* psrc = ws + WS_PS + (size_t)bw * (96 * 64);
        for (int i = tid; i < 96 * 16; i += 256) {
            int j = i >> 4, c4 = (i & 15) * 4;
            *(float4*)&sF[j][c4] = *(const float4*)(fsrc + j * 64 + c4);
        }
        for (int i = tid; i < 96 * 4; i += 256) {
            int j = i >> 2, q = i & 3;
            const float4 p4 = *(const float4*)(psrc + j * 64 + dbase + 4 * q);
            sP[4 * q + 0][j] = p4.x; sP[4 * q + 1][j] = p4.y;
            sP[4 * q + 2][j] = p4.z; sP[4 * q + 3][j] = p4.w;
        }
    }
    if (tid < N_) {   // transforms for camera (b, tid) — validated f64 chain
        #pragma clang fp contract(off)
        int t = b * N_ + tid;
        double* X = sTd[tid];
        double PR[9], Kd[9], Rd[9], Bd[9];
        for (int i = 0; i < 9; ++i) PR[i] = (double)prots[t * 9 + i];
        for (int i = 0; i < 9; ++i) Kd[i] = (double)intr[t * 9 + i];
        for (int i = 0; i < 9; ++i) Rd[i] = (double)rots[t * 9 + i];
        for (int i = 0; i < 9; ++i) Bd[i] = (double)bda[b * 9 + i];
        double iPR[9]; inv3d(PR, iPR);
        for (int i = 0; i < 9; ++i) X[i] = iPR[i];
        for (int i = 0; i < 3; ++i) X[9 + i] = (double)ptrans[t * 3 + i];
        double iK[9];  inv3d(Kd, iK);
        double comb[9]; mm3d(Rd, iK, comb);
        for (int i = 0; i < 9; ++i) X[12 + i] = comb[i];
        for (int i = 0; i < 3; ++i) X[21 + i] = (double)trans[t * 3 + i];
        for (int i = 0; i < 9; ++i) X[24 + i] = Bd[i];
    }
    __syncthreads();
    if (tid < 96) {   // quadratic coeffs for column j (op-order == validated k0b)
        #pragma clang fp contract(off)
        int j = tid, n = j >> 4, h = j & 15;
        const double* T = sTd[n];
        const double xs = (w == 43) ? 703.0 : (double)w * (703.0 / 43.0);
        const double ys = (double)(h * 17);
        const double u0 = xs - T[9];
        const double u1 = ys - T[10];
        double pA[3], pB[3];
        #pragma unroll
        for (int k = 0; k < 3; ++k) {
            pA[k] = (T[3*k]*u0 + T[3*k+1]*u1) - T[3*k+2]*T[11];
            pB[k] = T[3*k+2];
        }
        double q0c[3] = { pA[0]*pA[2], pA[0]*pB[2] + pB[0]*pA[2], pB[0]*pB[2] };
        double q1c[3] = { pA[1]*pA[2], pA[1]*pB[2] + pB[1]*pA[2], pB[1]*pB[2] };
        double q2c[3] = { pA[2], pB[2], 0.0 };
        double rc[3][3], gc[3][3];
        #pragma unroll
        for (int r = 0; r < 3; ++r)
            #pragma unroll
            for (int k = 0; k < 3; ++k)
                rc[r][k] = ((T[12+3*r]*q0c[k] + T[13+3*r]*q1c[k]) + T[14+3*r]*q2c[k])
                           + ((k == 0) ? T[21+r] : 0.0);
        #pragma unroll
        for (int g = 0; g < 3; ++g)
            #pragma unroll
            for (int k = 0; k < 3; ++k)
                gc[g][k] = (T[24+3*g]*rc[0][k] + T[25+3*g]*rc[1][k]) + T[26+3*g]*rc[2][k];
        #pragma unroll
        for (int q = 0; q < 9; ++q) sG[j * 9 + q] = gc[q / 3][q % 3];
    }
    __syncthreads();

    {   // geometry: Horner evaluation (bit-matches validated f64 chain)
        const double BXY = (double)(-51.2000007629394531f);  // f32 value of BX-DX/2
        for (int idx = tid; idx < nd * 96; idx += 256) {
            int dl = idx / 96, j = idx - dl * 96;
            const double* G = &sG[j * 9];
            const double dsv = (double)(dbase + dl + 1);
            const double g0 = (G[2] * dsv + G[1]) * dsv + G[0];
            const double g1 = (G[5] * dsv + G[4]) * dsv + G[3];
            const double g2 = (G[8] * dsv + G[7]) * dsv + G[6];
            const double fx = floor((g0 - BXY) * 1.25);   // 1.25==1/0.8 exact
            const double fy = floor((g1 - BXY) * 1.25);
            const bool keep = (fx >= 0.0) & (fx < 128.0) & (fy >= 0.0) & (fy < 128.0) &
                              (g2 >= -10.0) & (g2 < 10.0);
            sv16[idx] = keep ? (unsigned short)((int)fx * NX + (int)fy)
                             : (unsigned short)0xFFFF;
        }
    }
    __syncthreads();

    {   // flags: parallel scan (16 threads/dl x 6 j) + shfl combine
        const int dl = tid >> 4, s = tid & 15;
        int u = -1, mix = 0;
        const int base = dl * 96 + s * 6;
        #pragma unroll
        for (int t = 0; t < 6; ++t) {
            int v = sv16[base + t];
            if (v != 0xFFFF) { if (u < 0) u = v; else if (v != u) mix = 1; }
        }
        #pragma unroll
        for (int msk = 1; msk < 16; msk <<= 1) {
            int uo = __shfl_xor(u, msk, 64);
            int mo = __shfl_xor(mix, msk, 64);
            mix = mix | mo | ((u >= 0 && uo >= 0 && uo != u) ? 1 : 0);
            u = (u < 0) ? uo : u;
        }
        if (s == 0 && dl < nd) sflag[dl] = mix ? -2 : u;
    }
    for (int idx = tid; idx < nd * 96; idx += 256) {
        if (sv16[idx] == 0xFFFF) {
            int dl = idx / 96, j = idx - dl * 96;
            sP[dl][j] = 0.0f;
        }
    }
    __syncthreads();

    // group-GEMM: C[d][c] = sum_j p[dl][j]*f[j][c]; thread = (dl, 4 ch)
    const int dl = tid >> 4, ci = tid & 15;
    if (dl < nd) {
        const int flag = sflag[dl];
        if (ci == 0)   // voxel entry for k2c (-1: invalid or mixed-handled)
            ((int*)(ws + WS_VOX))[bw * DEPN + dbase + dl] = (flag >= 0) ? flag : -1;
        if (flag >= 0) {
            float ax = 0.f, ay = 0.f, az = 0.f, aw = 0.f;
            for (int jj = 0; jj < 96; jj += 4) {
                const float4 pv = *(const float4*)&sP[dl][jj];
                const float4 f0 = *(const float4*)&sF[jj + 0][4 * ci];
                const float4 f1 = *(const float4*)&sF[jj + 1][4 * ci];
                const float4 f2 = *(const float4*)&sF[jj + 2][4 * ci];
                const float4 f3 = *(const float4*)&sF[jj + 3][4 * ci];
                ax = fmaf(pv.x, f0.x, ax); ay = fmaf(pv.x, f0.y, ay);
                az = fmaf(pv.x, f0.z, az); aw = fmaf(pv.x, f0.w, aw);
                ax = fmaf(pv.y, f1.x, ax); ay = fmaf(pv.y, f1.y, ay);
                az = fmaf(pv.y, f1.z, az); aw = fmaf(pv.y, f1.w, aw);
                ax = fmaf(pv.z, f2.x, ax); ay = fmaf(pv.z, f2.y, ay);
                az = fmaf(pv.z, f2.z, az); aw = fmaf(pv.z, f2.w, aw);
                ax = fmaf(pv.w, f3.x, ax); ay = fmaf(pv.w, f3.y, ay);
                az = fmaf(pv.w, f3.z, az); aw = fmaf(pv.w, f3.w, aw);
            }
            float4 st = { ax, ay, az, aw };
            *(float4*)&ws[WS_C + ((size_t)(bw * DEPN + dbase + dl)) * 64 + 4 * ci] = st;
        }
    }
    // rare per-point slow path for mixed groups (atomics into the k1-zeroed
    // dout; sets mixed flag so k2c switches to read-modify-write)
    for (int d2 = 0; d2 < nd; ++d2) {
        if (sflag[d2] == -2) {
            if (tid == 0) atomicOr((int*)(ws + WS_MIXF), 1);
            int c = tid & 63, g = tid >> 6;
            for (int jj = 0; jj < 24; ++jj) {
                int j = g * 24 + jj;
                int v = sv16[d2 * 96 + j];
                if (v != 0xFFFF)
                    atomicAdd(dout + (((size_t)(b * CT + c)) << 14) + v,
                              sP[d2][j] * sF[j][c]);
            }
        }
    }
}

// ---------------- K2c: voxel-chunk gather + sequential BEV store ----------------
// Block = (128-voxel chunk, b). Pure store when no mixed groups (saves the
// 16.8MB dout read); RMW fallback preserves full correctness otherwise.
#define CHUNK 128
__global__ __launch_bounds__(256) void k2c_scatter(const float* __restrict__ ws,
                                                   float* __restrict__ dout) {
    __shared__ float acc[64][CHUNK + 4];       // 33,792 B
    __shared__ int   sVox[FW * DEPN];          // 2596 ids
    __shared__ short sMatch[FW * DEPN];
    __shared__ int   nMatch;
    const int tid = threadIdx.x;
    const int base = blockIdx.x * CHUNK;
    const int b = blockIdx.y;
    for (int i = tid; i < 64 * (CHUNK + 4); i += 256) (&acc[0][0])[i] = 0.0f;
    if (tid == 0) nMatch = 0;
    const int* vsrc = (const int*)(ws + WS_VOX) + b * (FW * DEPN);
    for (int i = tid; i < FW * DEPN; i += 256) sVox[i] = vsrc[i];
    __syncthreads();
    for (int i = tid; i < FW * DEPN; i += 256) {
        int v = sVox[i];
        if ((unsigned)(v - base) < CHUNK) {
            int m = atomicAdd(&nMatch, 1);
            sMatch[m] = (short)i;
        }
    }
    __syncthreads();
    const int c = tid & 63, quarter = tid >> 6;
    const int nm = nMatch;
    for (int m = quarter; m < nm; m += 4) {
        int e = sMatch[m];
        int lv = sVox[e] - base;
        float val = ws[WS_C + ((size_t)b * (FW * DEPN) + e) * 64 + c];
        atomicAdd(&acc[c][lv], val);           // LDS float atomic; nm ~ 20
    }
    __syncthreads();
    const int mixed = ((const int*)(ws + WS_MIXF))[0];
    const int wave = tid >> 6, lane = tid & 63;
    float* outb = dout + (((size_t)(b * CT)) << 14) + base;
    if (!mixed) {   // pure store: k1 zeroed BEV, no other writers
        for (int r = wave; r < 64; r += 4) {
            float2 v = { acc[r][lane * 2], acc[r][lane * 2 + 1] };
            *(float2*)(outb + ((size_t)r << 14) + lane * 2) = v;
        }
    } else {        // mixed contributions already atomically in dout: +=
        for (int r = wave; r < 64; r += 4) {
            float2* dst = (float2*)(outb + ((size_t)r << 14) + lane * 2);
            float2 v = *dst;
            v.x += acc[r][lane * 2];
            v.y += acc[r][lane * 2 + 1];
            *dst = v;
        }
    }
}

// ---------------- launcher ----------------
extern "C" void kernel_launch(void* const* d_in, const int* in_sizes, int n_in,
                              void* d_out, int out_size, void* d_ws, size_t ws_size,
                              hipStream_t stream) {
    const float* x      = (const float*)d_in[0];
    const float* rots   = (const float*)d_in[1];
    const float* trans  = (const float*)d_in[2];
    const float* intr   = (const float*)d_in[3];
    const float* prots  = (const float*)d_in[4];
    const float* ptrans = (const float*)d_in[5];
    const float* bda    = (const float*)d_in[6];
    const float* W      = (const float*)d_in[7];
    const float* bias   = (const float*)d_in[8];
    float* out = (float*)d_out;
    float* ws  = (float*)d_ws;

    k1_gemm<<<dim3(HW / 64, B_ * N_), 256, 0, stream>>>(x, W, bias, ws, out);
    k2b_geom<<<dim3(B_ * FW, 4), 256, 0, stream>>>(rots, trans, intr, prots, ptrans,
                                                   bda, ws, out);
    k2c_scatter<<<dim3(NX * NX / CHUNK, B_), 256, 0, stream>>>(ws, out);
}

// Round 10
// 137.005 us; speedup vs baseline: 2.0000x; 1.0034x over previous
//
#include <hip/hip_runtime.h>
#include <math.h>

// ---------------- problem constants ----------------
#define CIN   512
#define NOUT  123      // DEPTH + CT
#define DEPN  59
#define CT    64
#define B_    4
#define N_    6
#define FH    16
#define FW    44
#define HW    704      // FH*FW
#define NPIX  (B_*N_*HW)          // 16896
#define NX    128
#define BEV_ELEMS (B_*CT*NX*NX)   // 4,194,304
#define DEPTH_OFF BEV_ELEMS

// ws layout (float offsets).
#define WS_WB   1920                       // (unused region kept for layout stability)
#define WS_PS   (WS_WB + 32768)            // p-slab  [row = bw*96 + n*16+h][64] (cols 0..58)
#define WS_FS   (WS_PS + NPIX*64)          // f-slab  [row][64]
#define WS_C    (WS_FS + NPIX*64)          // group rows [bw][59][64]
#define WS_VOX  (WS_C + B_*FW*DEPN*64)     // int [bw][59]
#define WS_OVN  (WS_VOX + B_*FW*DEPN)      // int overflow counter
#define WS_OVK  (WS_OVN + 8)               // overflow keys [(b<<14)|vox], cap 16384
#define WS_OVD  (WS_OVK + 16384)           // overflow rows [16384][64]
#define OVCAP   16384

typedef short bf16x8 __attribute__((ext_vector_type(8)));
typedef float f32x4  __attribute__((ext_vector_type(4)));

__device__ inline unsigned short f2bf(float f) {   // RNE f32->bf16
    unsigned u = __float_as_uint(f);
    return (unsigned short)((u + 0x7fffu + ((u >> 16) & 1u)) >> 16);
}

__device__ inline void inv3d(const double* m, double* o) {
    #pragma clang fp contract(off)
    double c00 = m[4]*m[8] - m[5]*m[7];
    double c01 = m[5]*m[6] - m[3]*m[8];
    double c02 = m[3]*m[7] - m[4]*m[6];
    double det = m[0]*c00 + m[1]*c01 + m[2]*c02;
    o[0] = c00/det; o[1] = (m[2]*m[7]-m[1]*m[8])/det; o[2] = (m[1]*m[5]-m[2]*m[4])/det;
    o[3] = c01/det; o[4] = (m[0]*m[8]-m[2]*m[6])/det; o[5] = (m[2]*m[3]-m[0]*m[5])/det;
    o[6] = c02/det; o[7] = (m[1]*m[6]-m[0]*m[7])/det; o[8] = (m[0]*m[4]-m[1]*m[3])/det;
}
__device__ inline void mm3d(const double* a, const double* b, double* o) {
    #pragma clang fp contract(off)
    for (int i = 0; i < 3; ++i)
        for (int k = 0; k < 3; ++k)
            o[i*3+k] = (a[i*3+0]*b[0*3+k] + a[i*3+1]*b[1*3+k]) + a[i*3+2]*b[2*3+k];
}

// ---------------- K1: bf16 MFMA GEMM + fused softmax, o-split for concurrency ----------------
// v10: 528 blocks (22 pixcols x 2 o-halves x 24 bn), 64pix x 64o per block.
// ohalf 0 owns o=0..63 (all DEPN=59 depth cols: softmax + ps + depth out +
// fs tail 59..63); ohalf 1 owns o=64..122 (bias + fs only). 37KB LDS ->
// 4 blocks/CU capacity; 2x resident waves vs v9 (k1 was concurrency-starved).
// BEV zero REMOVED: k2c pure-stores full coverage; mixed groups go to an
// overflow list instead of dout atomics.
#define K1A   4608                 // A tile shorts (64*72)
#define K1T   9216                 // shorts per buf (A + 64*72)
__global__ __launch_bounds__(256) void k1_gemm(const float* __restrict__ x,
                                               const float* __restrict__ W,
                                               const float* __restrict__ bias,
                                               float* __restrict__ ws,
                                               float* __restrict__ dout) {
    __shared__ __align__(16) unsigned short s16[2 * K1T];   // 36,864 B
    const int tid = threadIdx.x;
    const int wave = tid >> 6, lane = tid & 63;
    const int l15 = lane & 15, quad = lane >> 4;
    const int bn = blockIdx.y;
    const int px = blockIdx.x >> 1;
    const int oh = blockIdx.x & 1;
    const int pixbase = px * 64;
    const int o0 = oh * 64;
    const float* xg = x + (size_t)bn * CIN * HW + pixbase;
    const int cpack = tid >> 4;          // channel group of 4
    const int pix4 = (tid & 15) * 4;     // pixel group of 4
    const int wo  = tid >> 3;            // weight-stage row (0..31)
    const int wsub = tid & 7;            // weight-stage 16B sub-chunk

    f32x4 acc[4] = {};
    float4 xr0, xr1, xr2, xr3;           // 1-deep prefetch: x tile
    float4 wf[4];                        // 1-deep prefetch: 2 weight rows (f32)
    const float4 zf4 = {0.f, 0.f, 0.f, 0.f};
    {   // prologue ck=0
        const float* src = xg + (size_t)(4 * cpack) * HW + pix4;
        xr0 = *(const float4*)(src);
        xr1 = *(const float4*)(src + HW);
        xr2 = *(const float4*)(src + 2 * HW);
        xr3 = *(const float4*)(src + 3 * HW);
        #pragma unroll
        for (int i = 0; i < 2; ++i) {
            const int o = o0 + wo + 32 * i;
            if (o < NOUT) {
                const float* wp = W + (size_t)o * CIN + wsub * 8;
                wf[2 * i]     = *(const float4*)(wp);
                wf[2 * i + 1] = *(const float4*)(wp + 4);
            } else { wf[2 * i] = zf4; wf[2 * i + 1] = zf4; }
        }
    }
    #pragma unroll
    for (int it = 0; it < 8; ++it) {
        const int buf = it & 1;
        unsigned short* sa = s16 + buf * K1T;     // [64][72]
        unsigned short* sb = sa + K1A;            // [64][72]
        {   // staged regs -> LDS (waits prefetch vmcnt), converting to bf16
            const float* f0 = (const float*)&xr0; const float* f1 = (const float*)&xr1;
            const float* f2 = (const float*)&xr2; const float* f3 = (const float*)&xr3;
            #pragma unroll
            for (int i = 0; i < 4; ++i) {
                uint2 pk;
                pk.x = (unsigned)f2bf(f0[i]) | ((unsigned)f2bf(f1[i]) << 16);
                pk.y = (unsigned)f2bf(f2[i]) | ((unsigned)f2bf(f3[i]) << 16);
                *(uint2*)&sa[(pix4 + i) * 72 + 4 * cpack] = pk;
            }
            #pragma unroll
            for (int i = 0; i < 2; ++i) {
                const float* fw = (const float*)&wf[2 * i];
                uint4 pk;
                pk.x = (unsigned)f2bf(fw[0]) | ((unsigned)f2bf(fw[1]) << 16);
                pk.y = (unsigned)f2bf(fw[2]) | ((unsigned)f2bf(fw[3]) << 16);
                pk.z = (unsigned)f2bf(fw[4]) | ((unsigned)f2bf(fw[5]) << 16);
                pk.w = (unsigned)f2bf(fw[6]) | ((unsigned)f2bf(fw[7]) << 16);
                *(uint4*)&sb[(wo + 32 * i) * 72 + wsub * 8] = pk;
            }
        }
        if (it < 7) {   // prefetch next K-step (overlaps MFMA below)
            const int ck = (it + 1) * 64;
            const float* src = xg + (size_t)(ck + 4 * cpack) * HW + pix4;
            xr0 = *(const float4*)(src);
            xr1 = *(const float4*)(src + HW);
            xr2 = *(const float4*)(src + 2 * HW);
            xr3 = *(const float4*)(src + 3 * HW);
            #pragma unroll
            for (int i = 0; i < 2; ++i) {
                const int o = o0 + wo + 32 * i;
                if (o < NOUT) {
                    const float* wp = W + (size_t)o * CIN + ck + wsub * 8;
                    wf[2 * i]     = *(const float4*)(wp);
                    wf[2 * i + 1] = *(const float4*)(wp + 4);
                } else { wf[2 * i] = zf4; wf[2 * i + 1] = zf4; }
            }
        }
        __syncthreads();   // buf visible; buf^1 free (last read 2 iters ago)
        #pragma unroll
        for (int ks = 0; ks < 64; ks += 32) {
            const bf16x8 a = *(const bf16x8*)&sa[(wave * 16 + l15) * 72 + ks + quad * 8];
            #pragma unroll
            for (int nt = 0; nt < 4; ++nt) {
                const bf16x8 b = *(const bf16x8*)&sb[(nt * 16 + l15) * 72 + ks + quad * 8];
                acc[nt] = __builtin_amdgcn_mfma_f32_16x16x32_bf16(a, b, acc[nt], 0, 0, 0);
            }
        }
    }
    // epilogue. ohalf 0: softmax over o=0..58 (fully inside this block's cols),
    // ps + sred + fs tail. ohalf 1: bias + fs only.
    float* sred = (float*)s16;          // [64][65], overlays buf 0
    const int b = bn / N_, n = bn - b * N_;
    {
        float bb[4];
        #pragma unroll
        for (int nt = 0; nt < 4; ++nt) {
            int o = o0 + nt * 16 + l15;
            bb[nt] = (o < NOUT) ? bias[o] : 0.0f;
        }
        float* ps = ws + WS_PS;
        float* fs = ws + WS_FS;
        #pragma unroll
        for (int reg = 0; reg < 4; ++reg) {
            int pixl = wave * 16 + quad * 4 + reg;
            int pix = pixbase + pixl;
            int h = pix / FW, w = pix - h * FW;
            size_t row = (size_t)(b * FW + w) * 96 + n * FH + h;
            if (oh == 0) {
                float v[4]; float m = -INFINITY;
                #pragma unroll
                for (int nt = 0; nt < 4; ++nt) {
                    v[nt] = acc[nt][reg] + bb[nt];
                    if (nt * 16 + l15 < DEPN) m = fmaxf(m, v[nt]);
                }
                #pragma unroll
                for (int msk = 8; msk >= 1; msk >>= 1) m = fmaxf(m, __shfl_xor(m, msk, 64));
                float e[4], s = 0.0f;
                #pragma unroll
                for (int nt = 0; nt < 4; ++nt) {
                    e[nt] = (nt * 16 + l15 < DEPN) ? expf(v[nt] - m) : 0.0f;
                    s += e[nt];
                }
                #pragma unroll
                for (int msk = 8; msk >= 1; msk >>= 1) s += __shfl_xor(s, msk, 64);
                const float inv = 1.0f / s;
                #pragma unroll
                for (int nt = 0; nt < 4; ++nt) {
                    int o = nt * 16 + l15;
                    if (o < DEPN) {
                        float p = e[nt] * inv;
                        ps[row * 64 + o] = p;
                        sred[pixl * 65 + o] = p;
                    } else fs[row * 64 + (o - DEPN)] = v[nt];   // o in 59..63
                }
            } else {
                #pragma unroll
                for (int nt = 0; nt < 4; ++nt) {
                    int o = o0 + nt * 16 + l15;
                    if (o < NOUT) fs[row * 64 + (o - DEPN)] = acc[nt][reg] + bb[nt];
                }
            }
        }
    }
    __syncthreads();
    if (oh == 0) {   // coalesced depth write, 256B/store
        for (int o = wave; o < DEPN; o += 4)
            dout[DEPTH_OFF + ((size_t)bn * DEPN + o) * HW + pixbase + lane] =
                sred[lane * 65 + o];
    }
    if (blockIdx.x == 0 && blockIdx.y == 0 && tid == 0)
        ((int*)(ws + WS_OVN))[0] = 0;     // overflow counter (before k2b)
}

// ---------------- K2b: in-tile transforms+coeffs + Horner geometry + group-GEMM ----------------
// Group sums stream to WS_C; voxel ids to WS_VOX; mixed groups (structurally
// absent for this input) write per-point rows to the ws overflow list.
#define DQ2 16
__global__ __launch_bounds__(256) void k2b_geom(
        const float* __restrict__ rots,  const float* __restrict__ trans,
        const float* __restrict__ intr,  const float* __restrict__ prots,
        const float* __restrict__ ptrans,const float* __restrict__ bda,
        float* __restrict__ ws) {
    __shared__ float sF[96][64];               // feats
    __shared__ float sP[DQ2][100];             // p tile, transposed, 16B-aligned rows
    __shared__ unsigned short sv16[DQ2 * 96];  // voxel id or 0xFFFF
    __shared__ __align__(16) double sG[96 * 9];// quadratic coeffs per column
    __shared__ double sTd[N_][33];             // per-camera transform records
    __shared__ int sflag[DQ2];
    const int tid = threadIdx.x;
    const int bw = blockIdx.x;
    const int b = bw / FW, w = bw - b * FW;
    const int dbase = blockIdx.y * DQ2;
    const int nd = min(DQ2, DEPN - dbase);

    {   // stage F + P(transposed, coalesced float4)
        const float* fsrc = ws + WS_FS + (size_t)bw * (96 * 64);
        const float* psrc = ws + WS_PS + (size_t)bw * (96 * 64);
        for (int i = tid; i < 96 * 16; i += 256) {
            int j = i >> 4, c4 = (i & 15) * 4;
            *(float4*)&sF[j][c4] = *(const float4*)(fsrc + j * 64 + c4);
        }
        for (int i = tid; i < 96 * 4; i += 256) {
            int j = i >> 2, q = i & 3;
            const float4 p4 = *(const float4*)(psrc + j * 64 + dbase + 4 * q);
            sP[4 * q + 0][j] = p4.x; sP[4 * q + 1][j] = p4.y;
            sP[4 * q + 2][j] = p4.z; sP[4 * q + 3][j] = p4.w;
        }
    }
    if (tid < N_) {   // transforms for camera (b, tid) — validated f64 chain
        #pragma clang fp contract(off)
        int t = b * N_ + tid;
        double* X = sTd[tid];
        double PR[9], Kd[9], Rd[9], Bd[9];
        for (int i = 0; i < 9; ++i) PR[i] = (double)prots[t * 9 + i];
        for (int i = 0; i < 9; ++i) Kd[i] = (double)intr[t * 9 + i];
        for (int i = 0; i < 9; ++i) Rd[i] = (double)rots[t * 9 + i];
        for (int i = 0; i < 9; ++i) Bd[i] = (double)bda[b * 9 + i];
        double iPR[9]; inv3d(PR, iPR);
        for (int i = 0; i < 9; ++i) X[i] = iPR[i];
        for (int i = 0; i < 3; ++i) X[9 + i] = (double)ptrans[t * 3 + i];
        double iK[9];  inv3d(Kd, iK);
        double comb[9]; mm3d(Rd, iK, comb);
        for (int i = 0; i < 9; ++i) X[12 + i] = comb[i];
        for (int i = 0; i < 3; ++i) X[21 + i] = (double)trans[t * 3 + i];
        for (int i = 0; i < 9; ++i) X[24 + i] = Bd[i];
    }
    __syncthreads();
    if (tid < 96) {   // quadratic coeffs for column j (op-order == validated chain)
        #pragma clang fp contract(off)
        int j = tid, n = j >> 4, h = j & 15;
        const double* T = sTd[n];
        const double xs = (w == 43) ? 703.0 : (double)w * (703.0 / 43.0);
        const double ys = (double)(h * 17);
        const double u0 = xs - T[9];
        const double u1 = ys - T[10];
        double pA[3], pB[3];
        #pragma unroll
        for (int k = 0; k < 3; ++k) {
            pA[k] = (T[3*k]*u0 + T[3*k+1]*u1) - T[3*k+2]*T[11];
            pB[k] = T[3*k+2];
        }
        double q0c[3] = { pA[0]*pA[2], pA[0]*pB[2] + pB[0]*pA[2], pB[0]*pB[2] };
        double q1c[3] = { pA[1]*pA[2], pA[1]*pB[2] + pB[1]*pA[2], pB[1]*pB[2] };
        double q2c[3] = { pA[2], pB[2], 0.0 };
        double rc[3][3], gc[3][3];
        #pragma unroll
        for (int r = 0; r < 3; ++r)
            #pragma unroll
            for (int k = 0; k < 3; ++k)
                rc[r][k] = ((T[12+3*r]*q0c[k] + T[13+3*r]*q1c[k]) + T[14+3*r]*q2c[k])
                           + ((k == 0) ? T[21+r] : 0.0);
        #pragma unroll
        for (int g = 0; g < 3; ++g)
            #pragma unroll
            for (int k = 0; k < 3; ++k)
                gc[g][k] = (T[24+3*g]*rc[0][k] + T[25+3*g]*rc[1][k]) + T[26+3*g]*rc[2][k];
        #pragma unroll
        for (int q = 0; q < 9; ++q) sG[j * 9 + q] = gc[q / 3][q % 3];
    }
    __syncthreads();

    {   // geometry: Horner evaluation (bit-matches validated f64 chain)
        const double BXY = (double)(-51.2000007629394531f);  // f32 value of BX-DX/2
        for (int idx = tid; idx < nd * 96; idx += 256) {
            int dl = idx / 96, j = idx - dl * 96;
            const double* G = &sG[j * 9];
            const double dsv = (double)(dbase + dl + 1);
            const double g0 = (G[2] * dsv + G[1]) * dsv + G[0];
            const double g1 = (G[5] * dsv + G[4]) * dsv + G[3];
            const double g2 = (G[8] * dsv + G[7]) * dsv + G[6];
            const double fx = floor((g0 - BXY) * 1.25);   // 1.25==1/0.8 exact
            const double fy = floor((g1 - BXY) * 1.25);
            const bool keep = (fx >= 0.0) & (fx < 128.0) & (fy >= 0.0) & (fy < 128.0) &
                              (g2 >= -10.0) & (g2 < 10.0);
            sv16[idx] = keep ? (unsigned short)((int)fx * NX + (int)fy)
                             : (unsigned short)0xFFFF;
        }
    }
    __syncthreads();

    {   // flags: parallel scan (16 threads/dl x 6 j) + shfl combine
        const int dl = tid >> 4, s = tid & 15;
        int u = -1, mix = 0;
        const int base = dl * 96 + s * 6;
        #pragma unroll
        for (int t = 0; t < 6; ++t) {
            int v = sv16[base + t];
            if (v != 0xFFFF) { if (u < 0) u = v; else if (v != u) mix = 1; }
        }
        #pragma unroll
        for (int msk = 1; msk < 16; msk <<= 1) {
            int uo = __shfl_xor(u, msk, 64);
            int mo = __shfl_xor(mix, msk, 64);
            mix = mix | mo | ((u >= 0 && uo >= 0 && uo != u) ? 1 : 0);
            u = (u < 0) ? uo : u;
        }
        if (s == 0 && dl < nd) sflag[dl] = mix ? -2 : u;
    }
    for (int idx = tid; idx < nd * 96; idx += 256) {
        if (sv16[idx] == 0xFFFF) {
            int dl = idx / 96, j = idx - dl * 96;
            sP[dl][j] = 0.0f;
        }
    }
    __syncthreads();

    // group-GEMM: C[d][c] = sum_j p[dl][j]*f[j][c]; thread = (dl, 4 ch)
    const int dl = tid >> 4, ci = tid & 15;
    if (dl < nd) {
        const int flag = sflag[dl];
        if (ci == 0)   // voxel entry for k2c (-1: invalid or overflow-handled)
            ((int*)(ws + WS_VOX))[bw * DEPN + dbase + dl] = (flag >= 0) ? flag : -1;
        if (flag >= 0) {
            float ax = 0.f, ay = 0.f, az = 0.f, aw = 0.f;
            for (int jj = 0; jj < 96; jj += 4) {
                const float4 pv = *(const float4*)&sP[dl][jj];
                const float4 f0 = *(const float4*)&sF[jj + 0][4 * ci];
                const float4 f1 = *(const float4*)&sF[jj + 1][4 * ci];
                const float4 f2 = *(const float4*)&sF[jj + 2][4 * ci];
                const float4 f3 = *(const float4*)&sF[jj + 3][4 * ci];
                ax = fmaf(pv.x, f0.x, ax); ay = fmaf(pv.x, f0.y, ay);
                az = fmaf(pv.x, f0.z, az); aw = fmaf(pv.x, f0.w, aw);
                ax = fmaf(pv.y, f1.x, ax); ay = fmaf(pv.y, f1.y, ay);
                az = fmaf(pv.y, f1.z, az); aw = fmaf(pv.y, f1.w, aw);
                ax = fmaf(pv.z, f2.x, ax); ay = fmaf(pv.z, f2.y, ay);
                az = fmaf(pv.z, f2.z, az); aw = fmaf(pv.z, f2.w, aw);
                ax = fmaf(pv.w, f3.x, ax); ay = fmaf(pv.w, f3.y, ay);
                az = fmaf(pv.w, f3.z, az); aw = fmaf(pv.w, f3.w, aw);
            }
            float4 st = { ax, ay, az, aw };
            *(float4*)&ws[WS_C + ((size_t)(bw * DEPN + dbase + dl)) * 64 + 4 * ci] = st;
        }
    }
    // rare slow path for mixed groups: per-point rows into the overflow list
    for (int d2 = 0; d2 < nd; ++d2) {
        if (sflag[d2] == -2) {
            int c = tid & 63, g = tid >> 6;
            for (int jj = 0; jj < 24; ++jj) {
                int j = g * 24 + jj;
                int v = sv16[d2 * 96 + j];
                if (v != 0xFFFF) {        // wave-uniform condition (same j per wave)
                    int slot = 0;
                    if (c == 0) slot = atomicAdd((int*)(ws + WS_OVN), 1);
                    slot = __shfl(slot, 0, 64);
                    if (slot < OVCAP) {
                        if (c == 0) ((int*)(ws + WS_OVK))[slot] = (b << 14) | v;
                        ws[WS_OVD + (size_t)slot * 64 + c] = sP[d2][j] * sF[j][c];
                    }
                }
            }
        }
    }
}

// ---------------- K2c: voxel-chunk gather + sequential BEV pure-store ----------------
// Block = (128-voxel chunk, b). Full BEV coverage via pure stores (no zero
// needed). Overflow entries (mixed groups) folded into the LDS acc first.
#define CHUNK 128
__global__ __launch_bounds__(256) void k2c_scatter(const float* __restrict__ ws,
                                                   float* __restrict__ dout) {
    __shared__ float acc[64][CHUNK + 4];       // 33,792 B
    __shared__ int   sVox[FW * DEPN];          // 2596 ids
    __shared__ short sMatch[FW * DEPN];
    __shared__ int   nMatch;
    const int tid = threadIdx.x;
    const int base = blockIdx.x * CHUNK;
    const int b = blockIdx.y;
    for (int i = tid; i < 64 * (CHUNK + 4); i += 256) (&acc[0][0])[i] = 0.0f;
    if (tid == 0) nMatch = 0;
    const int* vsrc = (const int*)(ws + WS_VOX) + b * (FW * DEPN);
    for (int i = tid; i < FW * DEPN; i += 256) sVox[i] = vsrc[i];
    __syncthreads();
    for (int i = tid; i < FW * DEPN; i += 256) {
        int v = sVox[i];
        if ((unsigned)(v - base) < CHUNK) {
            int m = atomicAdd(&nMatch, 1);
            sMatch[m] = (short)i;
        }
    }
    __syncthreads();
    const int c = tid & 63, quarter = tid >> 6;
    const int nm = nMatch;
    for (int m = quarter; m < nm; m += 4) {
        int e = sMatch[m];
        int lv = sVox[e] - base;
        float val = ws[WS_C + ((size_t)b * (FW * DEPN) + e) * 64 + c];
        atomicAdd(&acc[c][lv], val);           // LDS float atomic; nm ~ 20
    }
    {   // overflow entries (mixed groups; normally 0)
        int nov = ((const int*)(ws + WS_OVN))[0];
        if (nov > OVCAP) nov = OVCAP;
        for (int m = quarter; m < nov; m += 4) {
            int key = ((const int*)(ws + WS_OVK))[m];
            int lv = (key & 16383) - base;
            if ((key >> 14) == b && (unsigned)lv < CHUNK)
                atomicAdd(&acc[c][lv], ws[WS_OVD + (size_t)m * 64 + c]);
        }
    }
    __syncthreads();
    // pure store: full chunk coverage, 512B coalesced per wave-row
    const int wave = tid >> 6, lane = tid & 63;
    float* outb = dout + (((size_t)(b * CT)) << 14) + base;
    for (int r = wave; r < 64; r += 4) {
        float2 v = { acc[r][lane * 2], acc[r][lane * 2 + 1] };
        *(float2*)(outb + ((size_t)r << 14) + lane * 2) = v;
    }
}

// ---------------- launcher ----------------
extern "C" void kernel_launch(void* const* d_in, const int* in_sizes, int n_in,
                              void* d_out, int out_size, void* d_ws, size_t ws_size,
                              hipStream_t stream) {
    const float* x      = (const float*)d_in[0];
    const float* rots   = (const float*)d_in[1];
    const float* trans  = (const float*)d_in[2];
    const float* intr   = (const float*)d_in[3];
    const float* prots  = (const float*)d_in[4];
    const float* ptrans = (const float*)d_in[5];
    const float* bda    = (const float*)d_in[6];
    const float* W      = (const float*)d_in[7];
    const float* bias   = (const float*)d_in[8];
    float* out = (float*)d_out;
    float* ws  = (float*)d_ws;

    k1_gemm<<<dim3((HW / 64) * 2, B_ * N_), 256, 0, stream>>>(x, W, bias, ws, out);
    k2b_geom<<<dim3(B_ * FW, 4), 256, 0, stream>>>(rots, trans, intr, prots, ptrans,
                                                   bda, ws);
    k2c_scatter<<<dim3(NX * NX / CHUNK, B_), 256, 0, stream>>>(ws, out);
}